// Round 3
// baseline (111.711 us; speedup 1.0000x reference)
//
#include <hip/hip_runtime.h>

// DirDist_P2P: fused jittered-query construction + exact 5-NN against two
// 2048-point clouds + inverse-distance UDF/grad + weighted scalar loss.
//
// R3: NQ=2 queries per thread (halves per-thread LDS reads: each 4-point
// ds_read_b128 group feeds two insert cascades), SUBS=16 (chunk=128),
// stride 388 dwords (16B-aligned; subs at banks 4s mod 32 -> 2-way = free).
// Final reduce fused via device-scope atomicAdd + last-block flag (ws
// zero-init by an 8-byte hipMemsetAsync node).

#define NPTS   2048
#define UPR    10
#define KNN    5
#define QTOT   (NPTS * UPR + NPTS)    // 22528
#define SUBS   16
#define CHUNK  (NPTS / SUBS)          // 128 points per sub-thread
#define CH_STRIDE 388                 // dwords; 388*4=1552 B (16B aligned), bank offset 4*sub
#define NQ     2
#define QPB    32                     // queries per block (256 thr * NQ / SUBS)
#define BLOCK  256
#define NBLOCKS (QTOT / QPB)          // 704

static __device__ __forceinline__ unsigned umin32(unsigned a, unsigned b) { return a < b ? a : b; }
static __device__ __forceinline__ unsigned umax32(unsigned a, unsigned b) { return a < b ? b : a; }

struct UdfResult { float udf, gx, gy, gz; };

// sorted-insert: b_i = min(b_i, max(b_{i-1}, p)), top-down (old values).
#define INSERT5(B0, B1, B2, B3, B4, p)       \
    do {                                     \
        unsigned _p = (p);                   \
        B4 = umin32(B4, umax32(B3, _p));     \
        B3 = umin32(B3, umax32(B2, _p));     \
        B2 = umin32(B2, umax32(B1, _p));     \
        B1 = umin32(B1, umax32(B0, _p));     \
        B0 = umin32(B0, _p);                 \
    } while (0)

#define DIST_PACK(px, py, pz, qx, qy, qz, idx, out)               \
    do {                                                          \
        float _dx = (qx) - (px), _dy = (qy) - (py), _dz = (qz) - (pz); \
        float _d2 = _dx * _dx + _dy * _dy + _dz * _dz;            \
        out = (__float_as_uint(_d2) & 0xFFFFF800u) | (idx);       \
    } while (0)

// 5-element sorted two-list merge (merge-path rank formula), in place on a*.
#define MERGE5(a0, a1, a2, a3, a4, c0, c1, c2, c3, c4)            \
    do {                                                          \
        unsigned n0 = umin32(a0, c0);                             \
        unsigned n1 = umin32(umin32(a1, c1), umax32(a0, c0));     \
        unsigned n2 = umin32(umin32(a2, c2),                      \
                      umin32(umax32(a1, c0), umax32(a0, c1)));    \
        unsigned n3 = umin32(umin32(a3, c3),                      \
                      umin32(umax32(a2, c0),                      \
                      umin32(umax32(a1, c1), umax32(a0, c2))));   \
        unsigned n4 = umin32(umin32(a4, c4),                      \
                      umin32(umax32(a3, c0),                      \
                      umin32(umax32(a2, c1),                      \
                      umin32(umax32(a1, c2), umax32(a0, c3)))));  \
        a0 = n0; a1 = n1; a2 = n2; a3 = n3; a4 = n4;              \
    } while (0)

// Scan one cloud for TWO queries sharing the point loads. All 16 sub-lanes of
// a query pair converge to identical results after the shuffle merge.
static __device__ __forceinline__ void process_cloud2(const float* lds,
                                                      float q0x, float q0y, float q0z,
                                                      float q1x, float q1y, float q1z,
                                                      int sub, UdfResult& r0, UdfResult& r1) {
    unsigned a0 = ~0u, a1 = ~0u, a2 = ~0u, a3 = ~0u, a4 = ~0u;   // query 0 list
    unsigned e0 = ~0u, e1 = ~0u, e2 = ~0u, e3 = ~0u, e4 = ~0u;   // query 1 list
    const float4* base4 = reinterpret_cast<const float4*>(lds + sub * CH_STRIDE);
    unsigned idx = (unsigned)(sub * CHUNK);

#pragma unroll 4
    for (int g = 0; g < CHUNK / 4; ++g) {
        float4 A = base4[3 * g + 0];   // p0.xyz p1.x
        float4 B = base4[3 * g + 1];   // p1.yz  p2.xy
        float4 C = base4[3 * g + 2];   // p2.z   p3.xyz
        unsigned p;

        DIST_PACK(A.x, A.y, A.z, q0x, q0y, q0z, idx, p); INSERT5(a0, a1, a2, a3, a4, p);
        DIST_PACK(A.x, A.y, A.z, q1x, q1y, q1z, idx, p); INSERT5(e0, e1, e2, e3, e4, p); ++idx;

        DIST_PACK(A.w, B.x, B.y, q0x, q0y, q0z, idx, p); INSERT5(a0, a1, a2, a3, a4, p);
        DIST_PACK(A.w, B.x, B.y, q1x, q1y, q1z, idx, p); INSERT5(e0, e1, e2, e3, e4, p); ++idx;

        DIST_PACK(B.z, B.w, C.x, q0x, q0y, q0z, idx, p); INSERT5(a0, a1, a2, a3, a4, p);
        DIST_PACK(B.z, B.w, C.x, q1x, q1y, q1z, idx, p); INSERT5(e0, e1, e2, e3, e4, p); ++idx;

        DIST_PACK(C.y, C.z, C.w, q0x, q0y, q0z, idx, p); INSERT5(a0, a1, a2, a3, a4, p);
        DIST_PACK(C.y, C.z, C.w, q1x, q1y, q1z, idx, p); INSERT5(e0, e1, e2, e3, e4, p); ++idx;
    }

    // merge the 16 sub-lists across lanes (xor 1,2,4,8), both queries.
#pragma unroll
    for (int mask = 1; mask <= 8; mask <<= 1) {
        unsigned c0 = (unsigned)__shfl_xor((int)a0, mask, 64);
        unsigned c1 = (unsigned)__shfl_xor((int)a1, mask, 64);
        unsigned c2 = (unsigned)__shfl_xor((int)a2, mask, 64);
        unsigned c3 = (unsigned)__shfl_xor((int)a3, mask, 64);
        unsigned c4 = (unsigned)__shfl_xor((int)a4, mask, 64);
        MERGE5(a0, a1, a2, a3, a4, c0, c1, c2, c3, c4);
        unsigned f0 = (unsigned)__shfl_xor((int)e0, mask, 64);
        unsigned f1 = (unsigned)__shfl_xor((int)e1, mask, 64);
        unsigned f2 = (unsigned)__shfl_xor((int)e2, mask, 64);
        unsigned f3 = (unsigned)__shfl_xor((int)e3, mask, 64);
        unsigned f4 = (unsigned)__shfl_xor((int)e4, mask, 64);
        MERGE5(e0, e1, e2, e3, e4, f0, f1, f2, f3, f4);
    }

    // inverse-distance weights -> udf grad. Exact d2 recomputed from idx.
    unsigned la[KNN] = { a0, a1, a2, a3, a4 };
    unsigned le[KNN] = { e0, e1, e2, e3, e4 };
#pragma unroll
    for (int which = 0; which < 2; ++which) {
        const unsigned* ls = which ? le : la;
        float qx = which ? q1x : q0x, qy = which ? q1y : q0y, qz = which ? q1z : q0z;
        float wsum = 0.f, gx = 0.f, gy = 0.f, gz = 0.f;
#pragma unroll
        for (int i = 0; i < KNN; ++i) {
            unsigned id = ls[i] & 0x7FFu;
            const float* pp = lds + (id >> 7) * CH_STRIDE + (id & 127u) * 3;
            float dx = qx - pp[0], dy = qy - pp[1], dz = qz - pp[2];
            float d2 = dx * dx + dy * dy + dz * dz;
            float inv = 1.0f / (d2 + 1e-8f);
            wsum += inv;
            gx += dx * inv; gy += dy * inv; gz += dz * inv;
        }
        float rs = 1.0f / wsum;
        gx *= rs; gy *= rs; gz *= rs;
        float ex = gx + 1e-10f, ey = gy + 1e-10f, ez = gz + 1e-10f;
        UdfResult& r = which ? r1 : r0;
        r.udf = sqrtf(ex * ex + ey * ey + ez * ez);
        r.gx = gx; r.gy = gy; r.gz = gz;
    }
}

static __device__ __forceinline__ float loss_term(const UdfResult& rt, const UdfResult& rs) {
    float ue  = fabsf(rt.udf - rs.udf);
    float uge = fabsf(rs.gx - rt.gx) + fabsf(rs.gy - rt.gy) + fabsf(rs.gz - rt.gz);
    float qw  = expf(-ue * 3.0f) * expf(-uge * 3.0f);
    return (ue + uge) * qw;
}

__global__ __launch_bounds__(BLOCK) void knn_loss_kernel(const float* __restrict__ src,
                                                         const float* __restrict__ tgt,
                                                         const float* __restrict__ noise,
                                                         float* __restrict__ acc,
                                                         unsigned* __restrict__ cnt,
                                                         float* __restrict__ out) {
    __shared__ float lt[SUBS * CH_STRIDE];   // tgt cloud, chunk-padded
    __shared__ float ls[SUBS * CH_STRIDE];   // src cloud, chunk-padded
    __shared__ float redw[BLOCK / 64];

    const int tid = threadIdx.x;

    // stage both clouds into LDS
    for (int p = tid; p < NPTS; p += BLOCK) {
        int c = p >> 7, l = p & 127;
        int db = c * CH_STRIDE + l * 3;
        lt[db + 0] = tgt[3 * p + 0];
        lt[db + 1] = tgt[3 * p + 1];
        lt[db + 2] = tgt[3 * p + 2];
        ls[db + 0] = src[3 * p + 0];
        ls[db + 1] = src[3 * p + 1];
        ls[db + 2] = src[3 * p + 2];
    }

    // two queries per thread (16 sub-lanes each, redundant across subs)
    const int sub = tid & 15;
    const int q0 = blockIdx.x * QPB + (tid >> 4) * NQ;
    const int q1 = q0 + 1;
    float q0x, q0y, q0z, q1x, q1y, q1z;
    {
        int m = q0 / UPR;   // q0 < NPTS*UPR always except in src-tail region
        if (q0 < NPTS * UPR) {
            q0x = tgt[3 * m + 0] + 0.05f * noise[3 * q0 + 0];
            q0y = tgt[3 * m + 1] + 0.05f * noise[3 * q0 + 1];
            q0z = tgt[3 * m + 2] + 0.05f * noise[3 * q0 + 2];
        } else {
            int i = q0 - NPTS * UPR;
            q0x = src[3 * i + 0]; q0y = src[3 * i + 1]; q0z = src[3 * i + 2];
        }
        int m1 = q1 / UPR;
        if (q1 < NPTS * UPR) {
            q1x = tgt[3 * m1 + 0] + 0.05f * noise[3 * q1 + 0];
            q1y = tgt[3 * m1 + 1] + 0.05f * noise[3 * q1 + 1];
            q1z = tgt[3 * m1 + 2] + 0.05f * noise[3 * q1 + 2];
        } else {
            int i = q1 - NPTS * UPR;
            q1x = src[3 * i + 0]; q1y = src[3 * i + 1]; q1z = src[3 * i + 2];
        }
    }

    __syncthreads();

    UdfResult rt0, rt1, rs0, rs1;
    process_cloud2(lt, q0x, q0y, q0z, q1x, q1y, q1z, sub, rt0, rt1);
    process_cloud2(ls, q0x, q0y, q0z, q1x, q1y, q1z, sub, rs0, rs1);

    float term = loss_term(rt0, rs0) + loss_term(rt1, rs1);
    float contrib = (sub == 0) ? term : 0.f;

    // wave butterfly sum
#pragma unroll
    for (int m = 1; m < 64; m <<= 1) contrib += __shfl_xor(contrib, m, 64);
    if ((tid & 63) == 0) redw[tid >> 6] = contrib;
    __syncthreads();

    if (tid == 0) {
        float partial = redw[0] + redw[1] + redw[2] + redw[3];
        atomicAdd(acc, partial);
        __threadfence();
        unsigned done = atomicAdd(cnt, 1u);
        if (done == NBLOCKS - 1) {
            float s = atomicAdd(acc, 0.0f);   // device-scope read after all adds
            out[0] = s / (float)QTOT;
        }
    }
}

extern "C" void kernel_launch(void* const* d_in, const int* in_sizes, int n_in,
                              void* d_out, int out_size, void* d_ws, size_t ws_size,
                              hipStream_t stream) {
    const float* src   = (const float*)d_in[0];
    const float* tgt   = (const float*)d_in[1];
    const float* noise = (const float*)d_in[2];
    float* out = (float*)d_out;
    float* acc = (float*)d_ws;                 // ws[0]: accumulator
    unsigned* cnt = (unsigned*)d_ws + 1;       // ws[1]: completion counter

    hipMemsetAsync(d_ws, 0, 8, stream);        // graph-capturable memset node
    knn_loss_kernel<<<NBLOCKS, BLOCK, 0, stream>>>(src, tgt, noise, acc, cnt, out);
}

// Round 4
// 104.677 us; speedup vs baseline: 1.0672x; 1.0672x over previous
//
#include <hip/hip_runtime.h>

// DirDist_P2P: fused jittered-query construction + exact 5-NN against two
// 2048-point clouds + inverse-distance UDF/grad + weighted scalar loss.
//
// R4: latency-bound fix. SUBS=16/NQ=1 (5632 waves, 2x R3), 512-thread blocks
// so 3 blocks/CU = 24 waves/CU under the same 49.6KB LDS (launch_bounds(512,6)
// caps VGPR<=85). Pair-insert (presort + merge-path into 5-list, min3-foldable,
// 14 ops/pair). Both clouds interleaved in one loop for 2x chain ILP.

#define NPTS   2048
#define UPR    10
#define KNN    5
#define QTOT   (NPTS * UPR + NPTS)    // 22528
#define SUBS   16
#define CHUNK  (NPTS / SUBS)          // 128 points per sub-thread
#define CH_STRIDE 388                 // dwords; 1552 B (16B aligned); banks 4*sub mod 32 -> 2-way (free)
#define BLOCK  512
#define QPB    (BLOCK / SUBS)         // 32 queries per block
#define NBLOCKS (QTOT / QPB)          // 704

static __device__ __forceinline__ unsigned umin32(unsigned a, unsigned b) { return a < b ? a : b; }
static __device__ __forceinline__ unsigned umax32(unsigned a, unsigned b) { return a < b ? b : a; }

struct UdfResult { float udf, gx, gy, gz; };

// Insert a PAIR of candidates into the sorted 5-list (ascending).
// Presort pair, then merge-path top-5 of (5-list ∪ 2-list). All maxes read
// OLD list values; min(min(x,y),z) folds to v_min3_u32.
#define INSERT_PAIR(A0, A1, A2, A3, A4, P, Q)                                  \
    do {                                                                       \
        unsigned _u = umin32(P, Q), _v = umax32(P, Q);                         \
        unsigned _m0u = umax32(A0, _u), _m1u = umax32(A1, _u);                 \
        unsigned _m2u = umax32(A2, _u), _m3u = umax32(A3, _u);                 \
        unsigned _m0v = umax32(A0, _v), _m1v = umax32(A1, _v);                 \
        unsigned _m2v = umax32(A2, _v);                                        \
        A0 = umin32(A0, _u);                                                   \
        A1 = umin32(umin32(A1, _v), _m0u);                                     \
        A2 = umin32(umin32(A2, _m1u), _m0v);                                   \
        A3 = umin32(umin32(A3, _m2u), _m1v);                                   \
        A4 = umin32(umin32(A4, _m3u), _m2v);                                   \
    } while (0)

#define DIST_KEY(px, py, pz, qx, qy, qz, idx, out)                             \
    do {                                                                       \
        float _dx = (qx) - (px), _dy = (qy) - (py), _dz = (qz) - (pz);         \
        float _d2 = _dx * _dx + _dy * _dy + _dz * _dz;                         \
        out = (__float_as_uint(_d2) & 0xFFFFF800u) | ((idx) & 0x7FFu);         \
    } while (0)

// 5+5 sorted merge (merge-path), in place on a*.
#define MERGE5(a0, a1, a2, a3, a4, c0, c1, c2, c3, c4)                         \
    do {                                                                       \
        unsigned n0 = umin32(a0, c0);                                          \
        unsigned n1 = umin32(umin32(a1, c1), umax32(a0, c0));                  \
        unsigned n2 = umin32(umin32(a2, c2),                                   \
                      umin32(umax32(a1, c0), umax32(a0, c1)));                 \
        unsigned n3 = umin32(umin32(a3, c3),                                   \
                      umin32(umax32(a2, c0),                                   \
                      umin32(umax32(a1, c1), umax32(a0, c2))));                \
        unsigned n4 = umin32(umin32(a4, c4),                                   \
                      umin32(umax32(a3, c0),                                   \
                      umin32(umax32(a2, c1),                                   \
                      umin32(umax32(a1, c2), umax32(a0, c3)))));               \
        a0 = n0; a1 = n1; a2 = n2; a3 = n3; a4 = n4;                           \
    } while (0)

// Epilogue: from 5 packed keys, recompute exact d2 and accumulate UDF/grad.
static __device__ __forceinline__ void udf_from_keys(const float* lds,
                                                     unsigned k0, unsigned k1, unsigned k2,
                                                     unsigned k3, unsigned k4,
                                                     float qx, float qy, float qz,
                                                     UdfResult& r) {
    unsigned ks[KNN] = { k0, k1, k2, k3, k4 };
    float wsum = 0.f, gx = 0.f, gy = 0.f, gz = 0.f;
#pragma unroll
    for (int i = 0; i < KNN; ++i) {
        unsigned id = ks[i] & 0x7FFu;
        const float* pp = lds + (id >> 7) * CH_STRIDE + (id & 127u) * 3;
        float dx = qx - pp[0], dy = qy - pp[1], dz = qz - pp[2];
        float d2 = dx * dx + dy * dy + dz * dz;
        float inv = 1.0f / (d2 + 1e-8f);
        wsum += inv;
        gx += dx * inv; gy += dy * inv; gz += dz * inv;
    }
    float rs = 1.0f / wsum;
    gx *= rs; gy *= rs; gz *= rs;
    float ex = gx + 1e-10f, ey = gy + 1e-10f, ez = gz + 1e-10f;
    r.udf = sqrtf(ex * ex + ey * ey + ez * ez);
    r.gx = gx; r.gy = gy; r.gz = gz;
}

__global__ __launch_bounds__(BLOCK, 6) void knn_loss_kernel(const float* __restrict__ src,
                                                            const float* __restrict__ tgt,
                                                            const float* __restrict__ noise,
                                                            float* __restrict__ acc,
                                                            unsigned* __restrict__ cnt,
                                                            float* __restrict__ out) {
    __shared__ float lt[SUBS * CH_STRIDE];   // tgt cloud, chunk-padded
    __shared__ float ls[SUBS * CH_STRIDE];   // src cloud, chunk-padded
    __shared__ float redw[BLOCK / 64];

    const int tid = threadIdx.x;

    // stage both clouds into LDS
    for (int p = tid; p < NPTS; p += BLOCK) {
        int c = p >> 7, l = p & 127;
        int db = c * CH_STRIDE + l * 3;
        lt[db + 0] = tgt[3 * p + 0];
        lt[db + 1] = tgt[3 * p + 1];
        lt[db + 2] = tgt[3 * p + 2];
        ls[db + 0] = src[3 * p + 0];
        ls[db + 1] = src[3 * p + 1];
        ls[db + 2] = src[3 * p + 2];
    }

    // one query per thread-group of 16 subs
    const int sub = tid & 15;
    const int q = blockIdx.x * QPB + (tid >> 4);
    float qx, qy, qz;
    if (q < NPTS * UPR) {
        int m = q / UPR;
        qx = tgt[3 * m + 0] + 0.05f * noise[3 * q + 0];
        qy = tgt[3 * m + 1] + 0.05f * noise[3 * q + 1];
        qz = tgt[3 * m + 2] + 0.05f * noise[3 * q + 2];
    } else {
        int i = q - NPTS * UPR;
        qx = src[3 * i + 0]; qy = src[3 * i + 1]; qz = src[3 * i + 2];
    }

    __syncthreads();

    // dual insert chains (tgt + src), interleaved for ILP
    unsigned t0 = ~0u, t1 = ~0u, t2 = ~0u, t3 = ~0u, t4 = ~0u;
    unsigned s0 = ~0u, s1 = ~0u, s2 = ~0u, s3 = ~0u, s4 = ~0u;
    {
        const float4* bt = reinterpret_cast<const float4*>(lt + sub * CH_STRIDE);
        const float4* bs = reinterpret_cast<const float4*>(ls + sub * CH_STRIDE);
        unsigned idx = (unsigned)(sub * CHUNK);

#pragma unroll 2
        for (int g = 0; g < CHUNK / 4; ++g) {
            float4 A = bt[3 * g + 0];    // p0.xyz p1.x
            float4 B = bt[3 * g + 1];    // p1.yz  p2.xy
            float4 C = bt[3 * g + 2];    // p2.z   p3.xyz
            float4 D = bs[3 * g + 0];
            float4 E = bs[3 * g + 1];
            float4 F = bs[3 * g + 2];
            unsigned p, qk;

            DIST_KEY(A.x, A.y, A.z, qx, qy, qz, idx + 0, p);
            DIST_KEY(A.w, B.x, B.y, qx, qy, qz, idx + 1, qk);
            INSERT_PAIR(t0, t1, t2, t3, t4, p, qk);
            DIST_KEY(D.x, D.y, D.z, qx, qy, qz, idx + 0, p);
            DIST_KEY(D.w, E.x, E.y, qx, qy, qz, idx + 1, qk);
            INSERT_PAIR(s0, s1, s2, s3, s4, p, qk);

            DIST_KEY(B.z, B.w, C.x, qx, qy, qz, idx + 2, p);
            DIST_KEY(C.y, C.z, C.w, qx, qy, qz, idx + 3, qk);
            INSERT_PAIR(t0, t1, t2, t3, t4, p, qk);
            DIST_KEY(E.z, E.w, F.x, qx, qy, qz, idx + 2, p);
            DIST_KEY(F.y, F.z, F.w, qx, qy, qz, idx + 3, qk);
            INSERT_PAIR(s0, s1, s2, s3, s4, p, qk);

            idx += 4;
        }
    }

    // merge the 16 sub-lists across lanes (xor 1,2,4,8), both clouds
#pragma unroll
    for (int mask = 1; mask <= 8; mask <<= 1) {
        unsigned c0 = (unsigned)__shfl_xor((int)t0, mask, 64);
        unsigned c1 = (unsigned)__shfl_xor((int)t1, mask, 64);
        unsigned c2 = (unsigned)__shfl_xor((int)t2, mask, 64);
        unsigned c3 = (unsigned)__shfl_xor((int)t3, mask, 64);
        unsigned c4 = (unsigned)__shfl_xor((int)t4, mask, 64);
        MERGE5(t0, t1, t2, t3, t4, c0, c1, c2, c3, c4);
        unsigned f0 = (unsigned)__shfl_xor((int)s0, mask, 64);
        unsigned f1 = (unsigned)__shfl_xor((int)s1, mask, 64);
        unsigned f2 = (unsigned)__shfl_xor((int)s2, mask, 64);
        unsigned f3 = (unsigned)__shfl_xor((int)s3, mask, 64);
        unsigned f4 = (unsigned)__shfl_xor((int)s4, mask, 64);
        MERGE5(s0, s1, s2, s3, s4, f0, f1, f2, f3, f4);
    }

    UdfResult rt, rs;
    udf_from_keys(lt, t0, t1, t2, t3, t4, qx, qy, qz, rt);
    udf_from_keys(ls, s0, s1, s2, s3, s4, qx, qy, qz, rs);

    float ue  = fabsf(rt.udf - rs.udf);
    float uge = fabsf(rs.gx - rt.gx) + fabsf(rs.gy - rt.gy) + fabsf(rs.gz - rt.gz);
    float qw  = expf(-ue * 3.0f) * expf(-uge * 3.0f);
    float term = (ue + uge) * qw;
    float contrib = (sub == 0) ? term : 0.f;

    // wave butterfly sum
#pragma unroll
    for (int m = 1; m < 64; m <<= 1) contrib += __shfl_xor(contrib, m, 64);
    if ((tid & 63) == 0) redw[tid >> 6] = contrib;
    __syncthreads();

    if (tid == 0) {
        float partial = 0.f;
#pragma unroll
        for (int w = 0; w < BLOCK / 64; ++w) partial += redw[w];
        atomicAdd(acc, partial);
        __threadfence();
        unsigned done = atomicAdd(cnt, 1u);
        if (done == NBLOCKS - 1) {
            float s = atomicAdd(acc, 0.0f);   // device-scope read after all adds
            out[0] = s / (float)QTOT;
        }
    }
}

extern "C" void kernel_launch(void* const* d_in, const int* in_sizes, int n_in,
                              void* d_out, int out_size, void* d_ws, size_t ws_size,
                              hipStream_t stream) {
    const float* src   = (const float*)d_in[0];
    const float* tgt   = (const float*)d_in[1];
    const float* noise = (const float*)d_in[2];
    float* out = (float*)d_out;
    float* acc = (float*)d_ws;                 // ws[0]: accumulator
    unsigned* cnt = (unsigned*)d_ws + 1;       // ws[1]: completion counter

    hipMemsetAsync(d_ws, 0, 8, stream);        // graph-capturable memset node
    knn_loss_kernel<<<NBLOCKS, BLOCK, 0, stream>>>(src, tgt, noise, acc, cnt, out);
}

// Round 5
// 102.185 us; speedup vs baseline: 1.0932x; 1.0244x over previous
//
#include <hip/hip_runtime.h>

// DirDist_P2P: fused jittered-query construction + exact 5-NN against two
// 2048-point clouds + inverse-distance UDF/grad + weighted scalar loss.
//
// R5: (a) points staged as float4(x,y,z,|p|^2); selection key =
// |p|^2 - 2q.p + (|q|^2 + 1e-4) via 3 fma + add (+and_or pack) — bias keeps
// keys positive under fp cancellation, order-isomorphic to d2; epilogue
// recomputes exact d2 from idx. (b) NQ=2 queries per thread share each
// ds_read_b128 (halves LDS traffic). (c) one cloud per block -> 33.3 KB LDS
// -> 4 blocks/CU = 32 waves/CU cap; SUBS=32, 1408 blocks. Small second
// kernel combines per-query results into the loss.

#define NPTS   2048
#define UPR    10
#define KNN    5
#define QTOT   (NPTS * UPR + NPTS)    // 22528
#define SUBS   32
#define CHUNK  (NPTS / SUBS)          // 64 points per sub-thread
#define CH4    65                     // float4 stride per chunk (64 + 1 pad -> banks 4s mod 32, 4/bank uniform)
#define BLOCK  512
#define NQ     2
#define QPB    (BLOCK * NQ / SUBS)    // 32 queries per block
#define NB1    (2 * QTOT / QPB)       // 1408 blocks (x2 clouds)
#define BLOCK2 256
#define NB2    (QTOT / BLOCK2)        // 88
#define BIAS   1e-4f

static __device__ __forceinline__ unsigned umin32(unsigned a, unsigned b) { return a < b ? a : b; }
static __device__ __forceinline__ unsigned umax32(unsigned a, unsigned b) { return a < b ? b : a; }

// Insert a PAIR of candidates into the sorted ascending 5-list.
#define INSERT_PAIR(A0, A1, A2, A3, A4, P, Q)                                  \
    do {                                                                       \
        unsigned _u = umin32(P, Q), _v = umax32(P, Q);                         \
        unsigned _m0u = umax32(A0, _u), _m1u = umax32(A1, _u);                 \
        unsigned _m2u = umax32(A2, _u), _m3u = umax32(A3, _u);                 \
        unsigned _m0v = umax32(A0, _v), _m1v = umax32(A1, _v);                 \
        unsigned _m2v = umax32(A2, _v);                                        \
        A0 = umin32(A0, _u);                                                   \
        A1 = umin32(umin32(A1, _v), _m0u);                                     \
        A2 = umin32(umin32(A2, _m1u), _m0v);                                   \
        A3 = umin32(umin32(A3, _m2u), _m1v);                                   \
        A4 = umin32(umin32(A4, _m3u), _m2v);                                   \
    } while (0)

// 5+5 sorted merge (merge-path), in place on a*.
#define MERGE5(a0, a1, a2, a3, a4, c0, c1, c2, c3, c4)                         \
    do {                                                                       \
        unsigned n0 = umin32(a0, c0);                                          \
        unsigned n1 = umin32(umin32(a1, c1), umax32(a0, c0));                  \
        unsigned n2 = umin32(umin32(a2, c2),                                   \
                      umin32(umax32(a1, c0), umax32(a0, c1)));                 \
        unsigned n3 = umin32(umin32(a3, c3),                                   \
                      umin32(umax32(a2, c0),                                   \
                      umin32(umax32(a1, c1), umax32(a0, c2))));                \
        unsigned n4 = umin32(umin32(a4, c4),                                   \
                      umin32(umax32(a3, c0),                                   \
                      umin32(umax32(a2, c1),                                   \
                      umin32(umax32(a1, c2), umax32(a0, c3)))));               \
        a0 = n0; a1 = n1; a2 = n2; a3 = n3; a4 = n4;                           \
    } while (0)

static __device__ __forceinline__ unsigned key_of(const float4& P, float qqb,
                                                  float n2x, float n2y, float n2z,
                                                  unsigned idxv) {
    float t = fmaf(P.x, n2x, fmaf(P.y, n2y, fmaf(P.z, n2z, P.w + qqb)));
    return (__float_as_uint(t) & 0xFFFFF800u) | idxv;   // v_and_or_b32
}

// Epilogue: exact d2 from idx -> UDF + grad, packed as float4(udf,gx,gy,gz).
static __device__ __forceinline__ float4 udf_from_keys(const float4* lds4,
                                                       unsigned k0, unsigned k1, unsigned k2,
                                                       unsigned k3, unsigned k4,
                                                       float qx, float qy, float qz) {
    unsigned ks[KNN] = { k0, k1, k2, k3, k4 };
    float wsum = 0.f, gx = 0.f, gy = 0.f, gz = 0.f;
#pragma unroll
    for (int i = 0; i < KNN; ++i) {
        unsigned id = ks[i] & 0x7FFu;
        float4 P = lds4[(id >> 6) * CH4 + (id & 63u)];
        float dx = qx - P.x, dy = qy - P.y, dz = qz - P.z;
        float d2 = dx * dx + dy * dy + dz * dz;
        float inv = 1.0f / (d2 + 1e-8f);
        wsum += inv;
        gx += dx * inv; gy += dy * inv; gz += dz * inv;
    }
    float rs = 1.0f / wsum;
    gx *= rs; gy *= rs; gz *= rs;
    float ex = gx + 1e-10f, ey = gy + 1e-10f, ez = gz + 1e-10f;
    return make_float4(sqrtf(ex * ex + ey * ey + ez * ez), gx, gy, gz);
}

__global__ __launch_bounds__(BLOCK, 8) void knn_kernel(const float* __restrict__ src,
                                                       const float* __restrict__ tgt,
                                                       const float* __restrict__ noise,
                                                       float4* __restrict__ res) {
    __shared__ float4 lds4[SUBS * CH4];   // 33280 B

    const int tid = threadIdx.x;
    const int cloud = blockIdx.x & 1;              // 0 = tgt, 1 = src
    const int qbase = (blockIdx.x >> 1) * QPB;
    const float* cpts = cloud ? src : tgt;

    // stage cloud: 4 points per thread as float4(x,y,z,|p|^2)
    {
        const float4* g4 = reinterpret_cast<const float4*>(cpts);
        float4 A = g4[3 * tid + 0];   // p0.xyz p1.x
        float4 B = g4[3 * tid + 1];   // p1.yz  p2.xy
        float4 C = g4[3 * tid + 2];   // p2.z   p3.xyz
        float w0 = fmaf(A.x, A.x, fmaf(A.y, A.y, A.z * A.z));
        float w1 = fmaf(A.w, A.w, fmaf(B.x, B.x, B.y * B.y));
        float w2 = fmaf(B.z, B.z, fmaf(B.w, B.w, C.x * C.x));
        float w3 = fmaf(C.y, C.y, fmaf(C.z, C.z, C.w * C.w));
        int db = (tid >> 4) * CH4 + (tid & 15) * 4;
        lds4[db + 0] = make_float4(A.x, A.y, A.z, w0);
        lds4[db + 1] = make_float4(A.w, B.x, B.y, w1);
        lds4[db + 2] = make_float4(B.z, B.w, C.x, w2);
        lds4[db + 3] = make_float4(C.y, C.z, C.w, w3);
    }

    // two queries per thread: q0 = qbase+u, q1 = qbase+u+16 (u = tid>>5)
    const int sub = tid & 31;
    const int u = tid >> 5;
    const int q0 = qbase + u;
    const int q1 = qbase + u + 16;

    float q0x, q0y, q0z, q1x, q1y, q1z;
    {
        if (q0 < NPTS * UPR) {
            int m = q0 / UPR;
            q0x = fmaf(0.05f, noise[3 * q0 + 0], tgt[3 * m + 0]);
            q0y = fmaf(0.05f, noise[3 * q0 + 1], tgt[3 * m + 1]);
            q0z = fmaf(0.05f, noise[3 * q0 + 2], tgt[3 * m + 2]);
        } else {
            int i = q0 - NPTS * UPR;
            q0x = src[3 * i + 0]; q0y = src[3 * i + 1]; q0z = src[3 * i + 2];
        }
        if (q1 < NPTS * UPR) {
            int m = q1 / UPR;
            q1x = fmaf(0.05f, noise[3 * q1 + 0], tgt[3 * m + 0]);
            q1y = fmaf(0.05f, noise[3 * q1 + 1], tgt[3 * m + 1]);
            q1z = fmaf(0.05f, noise[3 * q1 + 2], tgt[3 * m + 2]);
        } else {
            int i = q1 - NPTS * UPR;
            q1x = src[3 * i + 0]; q1y = src[3 * i + 1]; q1z = src[3 * i + 2];
        }
    }

    const float qqb0 = fmaf(q0x, q0x, fmaf(q0y, q0y, q0z * q0z)) + BIAS;
    const float qqb1 = fmaf(q1x, q1x, fmaf(q1y, q1y, q1z * q1z)) + BIAS;
    const float n0x = -2.f * q0x, n0y = -2.f * q0y, n0z = -2.f * q0z;
    const float n1x = -2.f * q1x, n1y = -2.f * q1y, n1z = -2.f * q1z;

    __syncthreads();

    unsigned a0 = ~0u, a1 = ~0u, a2 = ~0u, a3 = ~0u, a4 = ~0u;   // q0 list
    unsigned e0 = ~0u, e1 = ~0u, e2 = ~0u, e3 = ~0u, e4 = ~0u;   // q1 list
    {
        const float4* b4 = lds4 + sub * CH4;
        unsigned idx = (unsigned)(sub * CHUNK);
#pragma unroll 2
        for (int j = 0; j < CHUNK; j += 2) {
            float4 P = b4[j];
            float4 Q = b4[j + 1];
            unsigned kA = key_of(P, qqb0, n0x, n0y, n0z, idx);
            unsigned kB = key_of(Q, qqb0, n0x, n0y, n0z, idx + 1);
            INSERT_PAIR(a0, a1, a2, a3, a4, kA, kB);
            unsigned kC = key_of(P, qqb1, n1x, n1y, n1z, idx);
            unsigned kD = key_of(Q, qqb1, n1x, n1y, n1z, idx + 1);
            INSERT_PAIR(e0, e1, e2, e3, e4, kC, kD);
            idx += 2;
        }
    }

    // merge 32 sub-lists (xor 1..16 stays within each 32-lane query group)
#pragma unroll
    for (int mask = 1; mask <= 16; mask <<= 1) {
        unsigned c0 = (unsigned)__shfl_xor((int)a0, mask, 64);
        unsigned c1 = (unsigned)__shfl_xor((int)a1, mask, 64);
        unsigned c2 = (unsigned)__shfl_xor((int)a2, mask, 64);
        unsigned c3 = (unsigned)__shfl_xor((int)a3, mask, 64);
        unsigned c4 = (unsigned)__shfl_xor((int)a4, mask, 64);
        MERGE5(a0, a1, a2, a3, a4, c0, c1, c2, c3, c4);
        unsigned f0 = (unsigned)__shfl_xor((int)e0, mask, 64);
        unsigned f1 = (unsigned)__shfl_xor((int)e1, mask, 64);
        unsigned f2 = (unsigned)__shfl_xor((int)e2, mask, 64);
        unsigned f3 = (unsigned)__shfl_xor((int)e3, mask, 64);
        unsigned f4 = (unsigned)__shfl_xor((int)e4, mask, 64);
        MERGE5(e0, e1, e2, e3, e4, f0, f1, f2, f3, f4);
    }

    float4 r0 = udf_from_keys(lds4, a0, a1, a2, a3, a4, q0x, q0y, q0z);
    float4 r1 = udf_from_keys(lds4, e0, e1, e2, e3, e4, q1x, q1y, q1z);

    if (sub == 0) {
        res[cloud * QTOT + q0] = r0;
        res[cloud * QTOT + q1] = r1;
    }
}

__global__ __launch_bounds__(BLOCK2) void loss_kernel(const float4* __restrict__ res,
                                                      float* __restrict__ acc,
                                                      unsigned* __restrict__ cnt,
                                                      float* __restrict__ out) {
    const int q = blockIdx.x * BLOCK2 + threadIdx.x;
    float4 t = res[q];            // tgt-cloud result
    float4 s = res[QTOT + q];     // src-cloud result
    float ue  = fabsf(t.x - s.x);
    float uge = fabsf(s.y - t.y) + fabsf(s.z - t.z) + fabsf(s.w - t.w);
    float sum = ue + uge;
    float term = sum * expf(-3.0f * sum);

#pragma unroll
    for (int m = 1; m < 64; m <<= 1) term += __shfl_xor(term, m, 64);
    __shared__ float red[BLOCK2 / 64];
    if ((threadIdx.x & 63) == 0) red[threadIdx.x >> 6] = term;
    __syncthreads();

    if (threadIdx.x == 0) {
        float partial = 0.f;
#pragma unroll
        for (int w = 0; w < BLOCK2 / 64; ++w) partial += red[w];
        atomicAdd(acc, partial);
        __threadfence();
        unsigned done = atomicAdd(cnt, 1u);
        if (done == NB2 - 1) {
            float sfin = atomicAdd(acc, 0.0f);
            out[0] = sfin / (float)QTOT;
        }
    }
}

extern "C" void kernel_launch(void* const* d_in, const int* in_sizes, int n_in,
                              void* d_out, int out_size, void* d_ws, size_t ws_size,
                              hipStream_t stream) {
    const float* src   = (const float*)d_in[0];
    const float* tgt   = (const float*)d_in[1];
    const float* noise = (const float*)d_in[2];
    float* out = (float*)d_out;

    float* acc = (float*)d_ws;                               // ws[0]
    unsigned* cnt = (unsigned*)d_ws + 1;                     // ws[1]
    float4* res = (float4*)((char*)d_ws + 16);               // 2*QTOT float4 = 704.8 KB

    hipMemsetAsync(d_ws, 0, 8, stream);
    knn_kernel<<<NB1, BLOCK, 0, stream>>>(src, tgt, noise, res);
    loss_kernel<<<NB2, BLOCK2, 0, stream>>>(res, acc, cnt, out);
}

// Round 6
// 97.261 us; speedup vs baseline: 1.1486x; 1.0506x over previous
//
#include <hip/hip_runtime.h>

// DirDist_P2P: fused jittered-query construction + exact 5-NN against two
// 2048-point clouds + inverse-distance UDF/grad + weighted scalar loss.
//
// R6: NQ=4 queries per thread (each ds_read_b128 feeds 4 insert chains ->
// LDS wave-inst halves vs R5, conflicts halve, 4x chain ILP). SUBS=32,
// BLOCK=512, QPB=64, 704 blocks. Epilogue distributed: subs 0..3 each
// select+process one chain. launch_bounds(512,7) caps VGPR at 73 (no spill).

#define NPTS   2048
#define UPR    10
#define KNN    5
#define QTOT   (NPTS * UPR + NPTS)    // 22528
#define SUBS   32
#define CHUNK  (NPTS / SUBS)          // 64 points per sub-thread
#define CH4    65                     // float4 stride per chunk (64 + 1 pad)
#define BLOCK  512
#define NQ     4
#define QPB    (BLOCK / SUBS * NQ)    // 64 queries per block
#define NB1    (2 * QTOT / QPB)       // 704 blocks (x2 clouds)
#define BLOCK2 256
#define NB2    (QTOT / BLOCK2)        // 88
#define BIAS   1e-4f

static __device__ __forceinline__ unsigned umin32(unsigned a, unsigned b) { return a < b ? a : b; }
static __device__ __forceinline__ unsigned umax32(unsigned a, unsigned b) { return a < b ? b : a; }

// Insert a PAIR of candidates into the sorted ascending 5-list.
#define INSERT_PAIR(A0, A1, A2, A3, A4, P, Q)                                  \
    do {                                                                       \
        unsigned _u = umin32(P, Q), _v = umax32(P, Q);                         \
        unsigned _m0u = umax32(A0, _u), _m1u = umax32(A1, _u);                 \
        unsigned _m2u = umax32(A2, _u), _m3u = umax32(A3, _u);                 \
        unsigned _m0v = umax32(A0, _v), _m1v = umax32(A1, _v);                 \
        unsigned _m2v = umax32(A2, _v);                                        \
        A0 = umin32(A0, _u);                                                   \
        A1 = umin32(umin32(A1, _v), _m0u);                                     \
        A2 = umin32(umin32(A2, _m1u), _m0v);                                   \
        A3 = umin32(umin32(A3, _m2u), _m1v);                                   \
        A4 = umin32(umin32(A4, _m3u), _m2v);                                   \
    } while (0)

// 5+5 sorted merge (merge-path), in place on a*.
#define MERGE5(a0, a1, a2, a3, a4, c0, c1, c2, c3, c4)                         \
    do {                                                                       \
        unsigned _n0 = umin32(a0, c0);                                         \
        unsigned _n1 = umin32(umin32(a1, c1), umax32(a0, c0));                 \
        unsigned _n2 = umin32(umin32(a2, c2),                                  \
                       umin32(umax32(a1, c0), umax32(a0, c1)));                \
        unsigned _n3 = umin32(umin32(a3, c3),                                  \
                       umin32(umax32(a2, c0),                                  \
                       umin32(umax32(a1, c1), umax32(a0, c2))));               \
        unsigned _n4 = umin32(umin32(a4, c4),                                  \
                       umin32(umax32(a3, c0),                                  \
                       umin32(umax32(a2, c1),                                  \
                       umin32(umax32(a1, c2), umax32(a0, c3)))));              \
        a0 = _n0; a1 = _n1; a2 = _n2; a3 = _n3; a4 = _n4;                      \
    } while (0)

#define SHFL_MERGE(a0, a1, a2, a3, a4, mask)                                   \
    do {                                                                       \
        unsigned _c0 = (unsigned)__shfl_xor((int)a0, mask, 64);                \
        unsigned _c1 = (unsigned)__shfl_xor((int)a1, mask, 64);                \
        unsigned _c2 = (unsigned)__shfl_xor((int)a2, mask, 64);                \
        unsigned _c3 = (unsigned)__shfl_xor((int)a3, mask, 64);                \
        unsigned _c4 = (unsigned)__shfl_xor((int)a4, mask, 64);                \
        MERGE5(a0, a1, a2, a3, a4, _c0, _c1, _c2, _c3, _c4);                   \
    } while (0)

static __device__ __forceinline__ unsigned key_of(const float4& P, float qqb,
                                                  float nx, float ny, float nz,
                                                  unsigned idxv) {
    float t = fmaf(P.x, nx, fmaf(P.y, ny, fmaf(P.z, nz, P.w + qqb)));
    return (__float_as_uint(t) & 0xFFFFF800u) | idxv;   // v_and_or_b32
}

__global__ __launch_bounds__(BLOCK, 7) void knn_kernel(const float* __restrict__ src,
                                                       const float* __restrict__ tgt,
                                                       const float* __restrict__ noise,
                                                       float4* __restrict__ res) {
    __shared__ float4 lds4[SUBS * CH4];   // 33280 B

    const int tid = threadIdx.x;
    const int cloud = blockIdx.x & 1;              // 0 = tgt, 1 = src
    const int qbase = (blockIdx.x >> 1) * QPB;
    const float* cpts = cloud ? src : tgt;

    // stage cloud: 4 points per thread as float4(x,y,z,|p|^2)
    {
        const float4* g4 = reinterpret_cast<const float4*>(cpts);
        float4 A = g4[3 * tid + 0];   // p0.xyz p1.x
        float4 B = g4[3 * tid + 1];   // p1.yz  p2.xy
        float4 C = g4[3 * tid + 2];   // p2.z   p3.xyz
        float w0 = fmaf(A.x, A.x, fmaf(A.y, A.y, A.z * A.z));
        float w1 = fmaf(A.w, A.w, fmaf(B.x, B.x, B.y * B.y));
        float w2 = fmaf(B.z, B.z, fmaf(B.w, B.w, C.x * C.x));
        float w3 = fmaf(C.y, C.y, fmaf(C.z, C.z, C.w * C.w));
        int db = (tid >> 4) * CH4 + (tid & 15) * 4;
        lds4[db + 0] = make_float4(A.x, A.y, A.z, w0);
        lds4[db + 1] = make_float4(A.w, B.x, B.y, w1);
        lds4[db + 2] = make_float4(B.z, B.w, C.x, w2);
        lds4[db + 3] = make_float4(C.y, C.z, C.w, w3);
    }

    // four queries per 32-lane group: q_c = qbase + u + 16*c, c=0..3
    const int sub = tid & 31;
    const int u = tid >> 5;           // 0..15

    float nx[NQ], ny[NQ], nz[NQ], qqb[NQ];
#pragma unroll
    for (int c = 0; c < NQ; ++c) {
        int q = qbase + u + 16 * c;
        float qx, qy, qz;
        if (q < NPTS * UPR) {
            int m = q / UPR;
            qx = fmaf(0.05f, noise[3 * q + 0], tgt[3 * m + 0]);
            qy = fmaf(0.05f, noise[3 * q + 1], tgt[3 * m + 1]);
            qz = fmaf(0.05f, noise[3 * q + 2], tgt[3 * m + 2]);
        } else {
            int i = q - NPTS * UPR;
            qx = src[3 * i + 0]; qy = src[3 * i + 1]; qz = src[3 * i + 2];
        }
        nx[c] = -2.f * qx; ny[c] = -2.f * qy; nz[c] = -2.f * qz;
        qqb[c] = fmaf(qx, qx, fmaf(qy, qy, qz * qz)) + BIAS;
    }

    __syncthreads();

    unsigned a0 = ~0u, a1 = ~0u, a2 = ~0u, a3 = ~0u, a4 = ~0u;   // chain q0
    unsigned b0 = ~0u, b1 = ~0u, b2 = ~0u, b3 = ~0u, b4 = ~0u;   // chain q1
    unsigned c0 = ~0u, c1 = ~0u, c2 = ~0u, c3 = ~0u, c4 = ~0u;   // chain q2
    unsigned d0 = ~0u, d1 = ~0u, d2 = ~0u, d3 = ~0u, d4 = ~0u;   // chain q3
    {
        const float4* bp = lds4 + sub * CH4;
        unsigned idx = (unsigned)(sub * CHUNK);
#pragma unroll 2
        for (int j = 0; j < CHUNK; j += 2) {
            float4 P = bp[j];
            float4 Q = bp[j + 1];
            unsigned kP, kQ;
            kP = key_of(P, qqb[0], nx[0], ny[0], nz[0], idx);
            kQ = key_of(Q, qqb[0], nx[0], ny[0], nz[0], idx + 1);
            INSERT_PAIR(a0, a1, a2, a3, a4, kP, kQ);
            kP = key_of(P, qqb[1], nx[1], ny[1], nz[1], idx);
            kQ = key_of(Q, qqb[1], nx[1], ny[1], nz[1], idx + 1);
            INSERT_PAIR(b0, b1, b2, b3, b4, kP, kQ);
            kP = key_of(P, qqb[2], nx[2], ny[2], nz[2], idx);
            kQ = key_of(Q, qqb[2], nx[2], ny[2], nz[2], idx + 1);
            INSERT_PAIR(c0, c1, c2, c3, c4, kP, kQ);
            kP = key_of(P, qqb[3], nx[3], ny[3], nz[3], idx);
            kQ = key_of(Q, qqb[3], nx[3], ny[3], nz[3], idx + 1);
            INSERT_PAIR(d0, d1, d2, d3, d4, kP, kQ);
            idx += 2;
        }
    }

    // merge 32 sub-lists per chain (xor 1..16 stays within 32-lane halves)
#pragma unroll
    for (int mask = 1; mask <= 16; mask <<= 1) {
        SHFL_MERGE(a0, a1, a2, a3, a4, mask);
        SHFL_MERGE(b0, b1, b2, b3, b4, mask);
        SHFL_MERGE(c0, c1, c2, c3, c4, mask);
        SHFL_MERGE(d0, d1, d2, d3, d4, mask);
    }

    // distributed epilogue: sub s (s<4 writes) handles chain s2 = sub&3
    const int s2 = sub & 3;
    unsigned k0 = s2 == 0 ? a0 : s2 == 1 ? b0 : s2 == 2 ? c0 : d0;
    unsigned k1 = s2 == 0 ? a1 : s2 == 1 ? b1 : s2 == 2 ? c1 : d1;
    unsigned k2 = s2 == 0 ? a2 : s2 == 1 ? b2 : s2 == 2 ? c2 : d2;
    unsigned k3 = s2 == 0 ? a3 : s2 == 1 ? b3 : s2 == 2 ? c3 : d3;
    unsigned k4 = s2 == 0 ? a4 : s2 == 1 ? b4 : s2 == 2 ? c4 : d4;
    float snx = s2 == 0 ? nx[0] : s2 == 1 ? nx[1] : s2 == 2 ? nx[2] : nx[3];
    float sny = s2 == 0 ? ny[0] : s2 == 1 ? ny[1] : s2 == 2 ? ny[2] : ny[3];
    float snz = s2 == 0 ? nz[0] : s2 == 1 ? nz[1] : s2 == 2 ? nz[2] : nz[3];
    float qx = -0.5f * snx, qy = -0.5f * sny, qz = -0.5f * snz;   // exact

    unsigned ks[KNN] = { k0, k1, k2, k3, k4 };
    float wsum = 0.f, gx = 0.f, gy = 0.f, gz = 0.f;
#pragma unroll
    for (int i = 0; i < KNN; ++i) {
        unsigned id = ks[i] & 0x7FFu;
        float4 P = lds4[(id >> 6) * CH4 + (id & 63u)];
        float dx = qx - P.x, dy = qy - P.y, dz = qz - P.z;
        float dd = dx * dx + dy * dy + dz * dz;
        float inv = 1.0f / (dd + 1e-8f);
        wsum += inv;
        gx += dx * inv; gy += dy * inv; gz += dz * inv;
    }
    float rs = 1.0f / wsum;
    gx *= rs; gy *= rs; gz *= rs;
    float ex = gx + 1e-10f, ey = gy + 1e-10f, ez = gz + 1e-10f;
    float udf = sqrtf(ex * ex + ey * ey + ez * ez);

    if (sub < NQ) {
        int q = qbase + u + 16 * s2;
        res[cloud * QTOT + q] = make_float4(udf, gx, gy, gz);
    }
}

__global__ __launch_bounds__(BLOCK2) void loss_kernel(const float4* __restrict__ res,
                                                      float* __restrict__ acc,
                                                      unsigned* __restrict__ cnt,
                                                      float* __restrict__ out) {
    const int q = blockIdx.x * BLOCK2 + threadIdx.x;
    float4 t = res[q];            // tgt-cloud result
    float4 s = res[QTOT + q];     // src-cloud result
    float ue  = fabsf(t.x - s.x);
    float uge = fabsf(s.y - t.y) + fabsf(s.z - t.z) + fabsf(s.w - t.w);
    float sum = ue + uge;
    float term = sum * expf(-3.0f * sum);

#pragma unroll
    for (int m = 1; m < 64; m <<= 1) term += __shfl_xor(term, m, 64);
    __shared__ float red[BLOCK2 / 64];
    if ((threadIdx.x & 63) == 0) red[threadIdx.x >> 6] = term;
    __syncthreads();

    if (threadIdx.x == 0) {
        float partial = 0.f;
#pragma unroll
        for (int w = 0; w < BLOCK2 / 64; ++w) partial += red[w];
        atomicAdd(acc, partial);
        __threadfence();
        unsigned done = atomicAdd(cnt, 1u);
        if (done == NB2 - 1) {
            float sfin = atomicAdd(acc, 0.0f);
            out[0] = sfin / (float)QTOT;
        }
    }
}

extern "C" void kernel_launch(void* const* d_in, const int* in_sizes, int n_in,
                              void* d_out, int out_size, void* d_ws, size_t ws_size,
                              hipStream_t stream) {
    const float* src   = (const float*)d_in[0];
    const float* tgt   = (const float*)d_in[1];
    const float* noise = (const float*)d_in[2];
    float* out = (float*)d_out;

    float* acc = (float*)d_ws;                               // ws[0]
    unsigned* cnt = (unsigned*)d_ws + 1;                     // ws[1]
    float4* res = (float4*)((char*)d_ws + 16);               // 2*QTOT float4

    hipMemsetAsync(d_ws, 0, 8, stream);
    knn_kernel<<<NB1, BLOCK, 0, stream>>>(src, tgt, noise, res);
    loss_kernel<<<NB2, BLOCK2, 0, stream>>>(res, acc, cnt, out);
}

// Round 7
// 91.831 us; speedup vs baseline: 1.2165x; 1.0591x over previous
//
#include <hip/hip_runtime.h>

// DirDist_P2P: fused jittered-query construction + exact 5-NN against two
// 2048-point clouds + inverse-distance UDF/grad + weighted scalar loss.
//
// R7: algorithmic pruning. The 20480 jittered queries come in groups of 10
// sharing center tgt[m]. Per (center, cloud) one wave: pass1 scans the cloud
// (lanes=points) for an upper bound r5ub of the center's 5th-NN distance
// (per-lane top-2 + butterfly merge); pass2 rescans, ballot-accepting points
// with d(p,c) <= r5ub + 2*deltamax (+fp margins) — provably a superset of
// every group member's true 5NN — and serially inserts the ~60-120 accepted
// points into 10 per-lane query chains via shfl broadcast. Exact selection.
// The 2048 tail queries (= src points, delta=0) keep the proven R6 dense
// path (NQ=4, SUBS=32) as blocks >= NGRPB of the same kernel.

#define NPTS   2048
#define UPR    10
#define KNN    5
#define NTGTQ  (NPTS * UPR)           // 20480
#define QTOT   (NTGTQ + NPTS)         // 22528
#define BIAS   1e-4f
#define BLOCK  256

// tail-dense params (R6 machinery at 256 threads)
#define SUBS   32
#define CHUNK  64
#define CH4    65                     // float4 chunk stride (64 + 1 pad)
#define TQPB   32                     // tail queries per block (8 groups x NQ 4)
#define NTAILB (2 * NPTS / TQPB)      // 128 tail blocks
#define NGRPB  1024                   // group blocks (4 waves = 4 tasks each)
#define NB_MAIN (NGRPB + NTAILB)      // 1152
#define BLOCK2 256
#define NB2    (QTOT / BLOCK2)        // 88

static __device__ __forceinline__ unsigned umin32(unsigned a, unsigned b) { return a < b ? a : b; }
static __device__ __forceinline__ unsigned umax32(unsigned a, unsigned b) { return a < b ? b : a; }

// single-candidate sorted insert (ascending 5-list), 9 min/max
#define INSERT1(A0, A1, A2, A3, A4, P)                                         \
    do {                                                                       \
        unsigned _p = (P);                                                     \
        A4 = umin32(A4, umax32(A3, _p));                                       \
        A3 = umin32(A3, umax32(A2, _p));                                       \
        A2 = umin32(A2, umax32(A1, _p));                                       \
        A1 = umin32(A1, umax32(A0, _p));                                       \
        A0 = umin32(A0, _p);                                                   \
    } while (0)

// pair insert (presort + merge-path), 14 min/max
#define INSERT_PAIR(A0, A1, A2, A3, A4, P, Q)                                  \
    do {                                                                       \
        unsigned _u = umin32(P, Q), _v = umax32(P, Q);                         \
        unsigned _m0u = umax32(A0, _u), _m1u = umax32(A1, _u);                 \
        unsigned _m2u = umax32(A2, _u), _m3u = umax32(A3, _u);                 \
        unsigned _m0v = umax32(A0, _v), _m1v = umax32(A1, _v);                 \
        unsigned _m2v = umax32(A2, _v);                                        \
        A0 = umin32(A0, _u);                                                   \
        A1 = umin32(umin32(A1, _v), _m0u);                                     \
        A2 = umin32(umin32(A2, _m1u), _m0v);                                   \
        A3 = umin32(umin32(A3, _m2u), _m1v);                                   \
        A4 = umin32(umin32(A4, _m3u), _m2v);                                   \
    } while (0)

// 5+5 sorted merge, u32 keys
#define MERGE5(a0, a1, a2, a3, a4, c0, c1, c2, c3, c4)                         \
    do {                                                                       \
        unsigned _n0 = umin32(a0, c0);                                         \
        unsigned _n1 = umin32(umin32(a1, c1), umax32(a0, c0));                 \
        unsigned _n2 = umin32(umin32(a2, c2),                                  \
                       umin32(umax32(a1, c0), umax32(a0, c1)));                \
        unsigned _n3 = umin32(umin32(a3, c3),                                  \
                       umin32(umax32(a2, c0),                                  \
                       umin32(umax32(a1, c1), umax32(a0, c2))));               \
        unsigned _n4 = umin32(umin32(a4, c4),                                  \
                       umin32(umax32(a3, c0),                                  \
                       umin32(umax32(a2, c1),                                  \
                       umin32(umax32(a1, c2), umax32(a0, c3)))));              \
        a0 = _n0; a1 = _n1; a2 = _n2; a3 = _n3; a4 = _n4;                      \
    } while (0)

#define SHFL_MERGE(a0, a1, a2, a3, a4, mask)                                   \
    do {                                                                       \
        unsigned _c0 = (unsigned)__shfl_xor((int)a0, mask, 64);                \
        unsigned _c1 = (unsigned)__shfl_xor((int)a1, mask, 64);                \
        unsigned _c2 = (unsigned)__shfl_xor((int)a2, mask, 64);                \
        unsigned _c3 = (unsigned)__shfl_xor((int)a3, mask, 64);                \
        unsigned _c4 = (unsigned)__shfl_xor((int)a4, mask, 64);                \
        MERGE5(a0, a1, a2, a3, a4, _c0, _c1, _c2, _c3, _c4);                   \
    } while (0)

// 5+5 sorted merge, f32 keys
#define FMERGE5(a0, a1, a2, a3, a4, c0, c1, c2, c3, c4)                        \
    do {                                                                       \
        float _g0 = fminf(a0, c0);                                             \
        float _g1 = fminf(fminf(a1, c1), fmaxf(a0, c0));                       \
        float _g2 = fminf(fminf(a2, c2),                                       \
                    fminf(fmaxf(a1, c0), fmaxf(a0, c1)));                      \
        float _g3 = fminf(fminf(a3, c3),                                       \
                    fminf(fmaxf(a2, c0),                                       \
                    fminf(fmaxf(a1, c1), fmaxf(a0, c2))));                     \
        float _g4 = fminf(fminf(a4, c4),                                       \
                    fminf(fmaxf(a3, c0),                                       \
                    fminf(fmaxf(a2, c1),                                       \
                    fminf(fmaxf(a1, c2), fmaxf(a0, c3)))));                    \
        a0 = _g0; a1 = _g1; a2 = _g2; a3 = _g3; a4 = _g4;                      \
    } while (0)

static __device__ __forceinline__ unsigned key_of(const float4& P, float qqb,
                                                  float nx, float ny, float nz,
                                                  unsigned idxv) {
    float t = fmaf(P.x, nx, fmaf(P.y, ny, fmaf(P.z, nz, P.w + qqb)));
    return (__float_as_uint(t) & 0xFFFFF800u) | idxv;
}

// Stage clouds as float4(x,y,z,|p|^2): i in [0,4096), cloud = i>>11.
__global__ __launch_bounds__(BLOCK) void prep_kernel(const float* __restrict__ src,
                                                     const float* __restrict__ tgt,
                                                     float4* __restrict__ cloud4) {
    int i = blockIdx.x * BLOCK + threadIdx.x;
    if (i >= 2 * NPTS) return;
    int pi = i & (NPTS - 1);
    const float* s = (i >> 11) ? src : tgt;
    float x = s[3 * pi + 0], y = s[3 * pi + 1], z = s[3 * pi + 2];
    float w = fmaf(x, x, fmaf(y, y, z * z));
    cloud4[i] = make_float4(x, y, z, w);
}

__global__ __launch_bounds__(BLOCK, 4) void main_kernel(const float* __restrict__ src,
                                                        const float* __restrict__ tgt,
                                                        const float* __restrict__ noise,
                                                        const float4* __restrict__ cloud4,
                                                        float4* __restrict__ res) {
    __shared__ float4 lds4[SUBS * CH4];   // used by tail-dense blocks only

    const int tid = threadIdx.x;

    if (blockIdx.x < NGRPB) {
        // ---------------- group path: one wave per (tgt-center, cloud) ----------------
        const int lane = tid & 63;
        const int task = blockIdx.x * 4 + (tid >> 6);   // 0..4095
        const int m = task >> 1;
        const int cloud = task & 1;
        const float4* c4 = cloud4 + cloud * NPTS;

        const float cx = tgt[3 * m + 0], cy = tgt[3 * m + 1], cz = tgt[3 * m + 2];

        // lane u < 10 owns query u of this group
        float qx = cx, qy = cy, qz = cz, delta = 0.f;
        if (lane < UPR) {
            int q = m * UPR + lane;
            float nr0 = noise[3 * q + 0], nr1 = noise[3 * q + 1], nr2 = noise[3 * q + 2];
            qx = fmaf(0.05f, nr0, cx);
            qy = fmaf(0.05f, nr1, cy);
            qz = fmaf(0.05f, nr2, cz);
            delta = 0.05f * sqrtf(fmaf(nr0, nr0, fmaf(nr1, nr1, nr2 * nr2)));
        }
        float dmax = delta;
#pragma unroll
        for (int s = 1; s < 64; s <<= 1) dmax = fmaxf(dmax, __shfl_xor(dmax, s, 64));

        const float ncx = -2.f * cx, ncy = -2.f * cy, ncz = -2.f * cz;
        const float ccb = fmaf(cx, cx, fmaf(cy, cy, cz * cz)) + BIAS;

        // pass 1: per-lane top-2 surrogate distances to center, merged -> r5 upper bound
        float f0 = INFINITY, f1 = INFINITY;
#pragma unroll 4
        for (int j = 0; j < NPTS / 64; ++j) {
            float4 P = c4[j * 64 + lane];
            float s = fmaf(P.x, ncx, fmaf(P.y, ncy, fmaf(P.z, ncz, P.w))) + ccb;
            f1 = fminf(f1, fmaxf(f0, s));
            f0 = fminf(f0, s);
        }
        float f2 = INFINITY, f3 = INFINITY, f4 = INFINITY;
#pragma unroll
        for (int s = 1; s < 64; s <<= 1) {
            float h0 = __shfl_xor(f0, s, 64), h1 = __shfl_xor(f1, s, 64),
                  h2 = __shfl_xor(f2, s, 64), h3 = __shfl_xor(f3, s, 64),
                  h4 = __shfl_xor(f4, s, 64);
            FMERGE5(f0, f1, f2, f3, f4, h0, h1, h2, h3, h4);
        }
        // r5ub >= true center 5th-NN distance (f4 is 5th of a SUBSET -> upper bound;
        // surrogate fp error covered by +2e-5 and +1e-3 slack)
        float r5ub = sqrtf(fmaxf(f4 - BIAS, 0.f) + 2e-5f) + 1e-3f;
        float bnd = r5ub + 2.f * dmax + 1e-3f;
        float S = fmaf(bnd, bnd, BIAS + 1e-5f);

        // per-query key constants
        const float nqx = -2.f * qx, nqy = -2.f * qy, nqz = -2.f * qz;
        const float qqb = fmaf(qx, qx, fmaf(qy, qy, qz * qz)) + BIAS;

        // pass 2: ballot-accept, serial broadcast + insert into per-lane chains
        unsigned b0 = ~0u, b1 = ~0u, b2 = ~0u, b3 = ~0u, b4 = ~0u;
        for (int j = 0; j < NPTS / 64; ++j) {
            const int base = j * 64;
            float4 P = c4[base + lane];
            float s = fmaf(P.x, ncx, fmaf(P.y, ncy, fmaf(P.z, ncz, P.w))) + ccb;
            unsigned long long mask = __ballot(s <= S);
            while (mask) {
                int b = __ffsll((unsigned long long)mask) - 1;
                mask &= mask - 1;
                float px = __shfl(P.x, b, 64);
                float py = __shfl(P.y, b, 64);
                float pz = __shfl(P.z, b, 64);
                float pw = __shfl(P.w, b, 64);
                unsigned idx = (unsigned)(base + b);
                float su = fmaf(px, nqx, fmaf(py, nqy, fmaf(pz, nqz, pw + qqb)));
                unsigned key = (__float_as_uint(su) & 0xFFFFF800u) | idx;
                INSERT1(b0, b1, b2, b3, b4, key);
            }
        }

        // exact epilogue per query (lane u < 10)
        if (lane < UPR) {
            unsigned ks[KNN] = { b0, b1, b2, b3, b4 };
            float wsum = 0.f, gx = 0.f, gy = 0.f, gz = 0.f;
#pragma unroll
            for (int i = 0; i < KNN; ++i) {
                unsigned id = ks[i] & 0x7FFu;
                float4 P = c4[id];
                float dx = qx - P.x, dy = qy - P.y, dz = qz - P.z;
                float dd = fmaf(dx, dx, fmaf(dy, dy, dz * dz));
                float inv = 1.0f / (dd + 1e-8f);
                wsum += inv;
                gx += dx * inv; gy += dy * inv; gz += dz * inv;
            }
            float rs = 1.0f / wsum;
            gx *= rs; gy *= rs; gz *= rs;
            float ex = gx + 1e-10f, ey = gy + 1e-10f, ez = gz + 1e-10f;
            float udf = sqrtf(fmaf(ex, ex, fmaf(ey, ey, ez * ez)));
            res[cloud * QTOT + m * UPR + lane] = make_float4(udf, gx, gy, gz);
        }
        return;
    }

    // ---------------- tail-dense path (R6 machinery, 256 threads) ----------------
    const int bb = blockIdx.x - NGRPB;          // 0..127
    const int cloud = bb & 1;
    const int qbase = NTGTQ + (bb >> 1) * TQPB;
    const float4* c4 = cloud4 + cloud * NPTS;

    // stage this cloud into LDS (chunk-padded) straight from cloud4
    for (int t = tid; t < 512; t += BLOCK) {
        int db = (t >> 4) * CH4 + (t & 15) * 4;
        lds4[db + 0] = c4[4 * t + 0];
        lds4[db + 1] = c4[4 * t + 1];
        lds4[db + 2] = c4[4 * t + 2];
        lds4[db + 3] = c4[4 * t + 3];
    }

    const int sub = tid & 31;
    const int u = tid >> 5;                     // 0..7

    // 4 queries per 32-lane group: q_c = qbase + u + 8*c (all tail -> src points)
    float nx[4], ny[4], nz[4], qqb[4];
#pragma unroll
    for (int c = 0; c < 4; ++c) {
        int i = qbase + u + 8 * c - NTGTQ;
        float qx = src[3 * i + 0], qy = src[3 * i + 1], qz = src[3 * i + 2];
        nx[c] = -2.f * qx; ny[c] = -2.f * qy; nz[c] = -2.f * qz;
        qqb[c] = fmaf(qx, qx, fmaf(qy, qy, qz * qz)) + BIAS;
    }

    __syncthreads();

    unsigned a0 = ~0u, a1 = ~0u, a2 = ~0u, a3 = ~0u, a4 = ~0u;
    unsigned e0 = ~0u, e1 = ~0u, e2 = ~0u, e3 = ~0u, e4 = ~0u;
    unsigned c0 = ~0u, c1 = ~0u, c2 = ~0u, c3 = ~0u, c4v = ~0u;
    unsigned d0 = ~0u, d1 = ~0u, d2 = ~0u, d3 = ~0u, d4 = ~0u;
    {
        const float4* bp = lds4 + sub * CH4;
        unsigned idx = (unsigned)(sub * CHUNK);
#pragma unroll 2
        for (int j = 0; j < CHUNK; j += 2) {
            float4 P = bp[j];
            float4 Q = bp[j + 1];
            unsigned kP, kQ;
            kP = key_of(P, qqb[0], nx[0], ny[0], nz[0], idx);
            kQ = key_of(Q, qqb[0], nx[0], ny[0], nz[0], idx + 1);
            INSERT_PAIR(a0, a1, a2, a3, a4, kP, kQ);
            kP = key_of(P, qqb[1], nx[1], ny[1], nz[1], idx);
            kQ = key_of(Q, qqb[1], nx[1], ny[1], nz[1], idx + 1);
            INSERT_PAIR(e0, e1, e2, e3, e4, kP, kQ);
            kP = key_of(P, qqb[2], nx[2], ny[2], nz[2], idx);
            kQ = key_of(Q, qqb[2], nx[2], ny[2], nz[2], idx + 1);
            INSERT_PAIR(c0, c1, c2, c3, c4v, kP, kQ);
            kP = key_of(P, qqb[3], nx[3], ny[3], nz[3], idx);
            kQ = key_of(Q, qqb[3], nx[3], ny[3], nz[3], idx + 1);
            INSERT_PAIR(d0, d1, d2, d3, d4, kP, kQ);
            idx += 2;
        }
    }

#pragma unroll
    for (int mask = 1; mask <= 16; mask <<= 1) {
        SHFL_MERGE(a0, a1, a2, a3, a4, mask);
        SHFL_MERGE(e0, e1, e2, e3, e4, mask);
        SHFL_MERGE(c0, c1, c2, c3, c4v, mask);
        SHFL_MERGE(d0, d1, d2, d3, d4, mask);
    }

    const int s2 = sub & 3;
    unsigned k0 = s2 == 0 ? a0 : s2 == 1 ? e0 : s2 == 2 ? c0 : d0;
    unsigned k1 = s2 == 0 ? a1 : s2 == 1 ? e1 : s2 == 2 ? c1 : d1;
    unsigned k2 = s2 == 0 ? a2 : s2 == 1 ? e2 : s2 == 2 ? c2 : d2;
    unsigned k3 = s2 == 0 ? a3 : s2 == 1 ? e3 : s2 == 2 ? c3 : d3;
    unsigned k4 = s2 == 0 ? a4 : s2 == 1 ? e4 : s2 == 2 ? c4v : d4;
    float snx = s2 == 0 ? nx[0] : s2 == 1 ? nx[1] : s2 == 2 ? nx[2] : nx[3];
    float sny = s2 == 0 ? ny[0] : s2 == 1 ? ny[1] : s2 == 2 ? ny[2] : ny[3];
    float snz = s2 == 0 ? nz[0] : s2 == 1 ? nz[1] : s2 == 2 ? nz[2] : nz[3];
    float qx = -0.5f * snx, qy = -0.5f * sny, qz = -0.5f * snz;

    unsigned ks[KNN] = { k0, k1, k2, k3, k4 };
    float wsum = 0.f, gx = 0.f, gy = 0.f, gz = 0.f;
#pragma unroll
    for (int i = 0; i < KNN; ++i) {
        unsigned id = ks[i] & 0x7FFu;
        float4 P = lds4[(id >> 6) * CH4 + (id & 63u)];
        float dx = qx - P.x, dy = qy - P.y, dz = qz - P.z;
        float dd = fmaf(dx, dx, fmaf(dy, dy, dz * dz));
        float inv = 1.0f / (dd + 1e-8f);
        wsum += inv;
        gx += dx * inv; gy += dy * inv; gz += dz * inv;
    }
    float rs = 1.0f / wsum;
    gx *= rs; gy *= rs; gz *= rs;
    float ex = gx + 1e-10f, ey = gy + 1e-10f, ez = gz + 1e-10f;
    float udf = sqrtf(fmaf(ex, ex, fmaf(ey, ey, ez * ez)));

    if (sub < 4) {
        int q = qbase + u + 8 * s2;
        res[cloud * QTOT + q] = make_float4(udf, gx, gy, gz);
    }
}

__global__ __launch_bounds__(BLOCK2) void loss_kernel(const float4* __restrict__ res,
                                                      float* __restrict__ acc,
                                                      unsigned* __restrict__ cnt,
                                                      float* __restrict__ out) {
    const int q = blockIdx.x * BLOCK2 + threadIdx.x;
    float4 t = res[q];
    float4 s = res[QTOT + q];
    float ue  = fabsf(t.x - s.x);
    float uge = fabsf(s.y - t.y) + fabsf(s.z - t.z) + fabsf(s.w - t.w);
    float sum = ue + uge;
    float term = sum * expf(-3.0f * sum);

#pragma unroll
    for (int m = 1; m < 64; m <<= 1) term += __shfl_xor(term, m, 64);
    __shared__ float red[BLOCK2 / 64];
    if ((threadIdx.x & 63) == 0) red[threadIdx.x >> 6] = term;
    __syncthreads();

    if (threadIdx.x == 0) {
        float partial = 0.f;
#pragma unroll
        for (int w = 0; w < BLOCK2 / 64; ++w) partial += red[w];
        atomicAdd(acc, partial);
        __threadfence();
        unsigned done = atomicAdd(cnt, 1u);
        if (done == NB2 - 1) {
            float sfin = atomicAdd(acc, 0.0f);
            out[0] = sfin / (float)QTOT;
        }
    }
}

extern "C" void kernel_launch(void* const* d_in, const int* in_sizes, int n_in,
                              void* d_out, int out_size, void* d_ws, size_t ws_size,
                              hipStream_t stream) {
    const float* src   = (const float*)d_in[0];
    const float* tgt   = (const float*)d_in[1];
    const float* noise = (const float*)d_in[2];
    float* out = (float*)d_out;

    float* acc = (float*)d_ws;                                     // ws[0]
    unsigned* cnt = (unsigned*)d_ws + 1;                           // ws[1]
    float4* cloud4 = (float4*)((char*)d_ws + 16);                  // 4096 float4 = 64 KB
    float4* res = (float4*)((char*)d_ws + 16 + 2 * NPTS * 16);     // 2*QTOT float4

    hipMemsetAsync(d_ws, 0, 8, stream);
    prep_kernel<<<(2 * NPTS + BLOCK - 1) / BLOCK, BLOCK, 0, stream>>>(src, tgt, cloud4);
    main_kernel<<<NB_MAIN, BLOCK, 0, stream>>>(src, tgt, noise, cloud4, res);
    loss_kernel<<<NB2, BLOCK2, 0, stream>>>(res, acc, cnt, out);
}

// Round 8
// 86.012 us; speedup vs baseline: 1.2988x; 1.0677x over previous
//
#include <hip/hip_runtime.h>

// DirDist_P2P: fused jittered-query construction + exact 5-NN against two
// 2048-point clouds + inverse-distance UDF/grad + weighted scalar loss.
//
// R8: group path pass2 = compact-then-parallel-insert. Ballot + mbcnt prefix
// compacts accepted (point,idx) into a per-wave LDS buffer (one end drain;
// overflow drains preserve correctness). Lane map sub*16+qi: 4 subs split the
// accepted list (~23 inserts/lane vs ~90 serial), 2 shfl_xor merges reunify.
// Tail (src queries) keeps R6 dense path, scheduled first. Harness ws poison
// (~40us fill of 268MB) is the fixed floor outside kernel control.

#define NPTS   2048
#define UPR    10
#define KNN    5
#define NTGTQ  (NPTS * UPR)           // 20480
#define QTOT   (NTGTQ + NPTS)         // 22528
#define BIAS   1e-4f
#define BLOCK  256

// tail-dense params
#define SUBS   32
#define CHUNK  64
#define CH4    65                     // float4 chunk stride (64 + 1 pad)
#define TQPB   32
#define NTAILB (2 * NPTS / TQPB)      // 128 tail blocks (first in grid)
#define NGRPB  1024                   // group blocks (4 wave-tasks each)
#define NB_MAIN (NTAILB + NGRPB)      // 1152
#define CAP    448                    // accepted-point buffer per wave
#define SM_BYTES 35840                // max(33280 tail, CAP*80 group)
#define BLOCK2 256
#define NB2    (QTOT / BLOCK2)        // 88

static __device__ __forceinline__ unsigned umin32(unsigned a, unsigned b) { return a < b ? a : b; }
static __device__ __forceinline__ unsigned umax32(unsigned a, unsigned b) { return a < b ? b : a; }

#define INSERT1(A0, A1, A2, A3, A4, P)                                         \
    do {                                                                       \
        unsigned _p = (P);                                                     \
        A4 = umin32(A4, umax32(A3, _p));                                       \
        A3 = umin32(A3, umax32(A2, _p));                                       \
        A2 = umin32(A2, umax32(A1, _p));                                       \
        A1 = umin32(A1, umax32(A0, _p));                                       \
        A0 = umin32(A0, _p);                                                   \
    } while (0)

#define INSERT_PAIR(A0, A1, A2, A3, A4, P, Q)                                  \
    do {                                                                       \
        unsigned _u = umin32(P, Q), _v = umax32(P, Q);                         \
        unsigned _m0u = umax32(A0, _u), _m1u = umax32(A1, _u);                 \
        unsigned _m2u = umax32(A2, _u), _m3u = umax32(A3, _u);                 \
        unsigned _m0v = umax32(A0, _v), _m1v = umax32(A1, _v);                 \
        unsigned _m2v = umax32(A2, _v);                                        \
        A0 = umin32(A0, _u);                                                   \
        A1 = umin32(umin32(A1, _v), _m0u);                                     \
        A2 = umin32(umin32(A2, _m1u), _m0v);                                   \
        A3 = umin32(umin32(A3, _m2u), _m1v);                                   \
        A4 = umin32(umin32(A4, _m3u), _m2v);                                   \
    } while (0)

#define MERGE5(a0, a1, a2, a3, a4, c0, c1, c2, c3, c4)                         \
    do {                                                                       \
        unsigned _n0 = umin32(a0, c0);                                         \
        unsigned _n1 = umin32(umin32(a1, c1), umax32(a0, c0));                 \
        unsigned _n2 = umin32(umin32(a2, c2),                                  \
                       umin32(umax32(a1, c0), umax32(a0, c1)));                \
        unsigned _n3 = umin32(umin32(a3, c3),                                  \
                       umin32(umax32(a2, c0),                                  \
                       umin32(umax32(a1, c1), umax32(a0, c2))));               \
        unsigned _n4 = umin32(umin32(a4, c4),                                  \
                       umin32(umax32(a3, c0),                                  \
                       umin32(umax32(a2, c1),                                  \
                       umin32(umax32(a1, c2), umax32(a0, c3)))));              \
        a0 = _n0; a1 = _n1; a2 = _n2; a3 = _n3; a4 = _n4;                      \
    } while (0)

#define SHFL_MERGE(a0, a1, a2, a3, a4, mask)                                   \
    do {                                                                       \
        unsigned _c0 = (unsigned)__shfl_xor((int)a0, mask, 64);                \
        unsigned _c1 = (unsigned)__shfl_xor((int)a1, mask, 64);                \
        unsigned _c2 = (unsigned)__shfl_xor((int)a2, mask, 64);                \
        unsigned _c3 = (unsigned)__shfl_xor((int)a3, mask, 64);                \
        unsigned _c4 = (unsigned)__shfl_xor((int)a4, mask, 64);                \
        MERGE5(a0, a1, a2, a3, a4, _c0, _c1, _c2, _c3, _c4);                   \
    } while (0)

#define FMERGE5(a0, a1, a2, a3, a4, c0, c1, c2, c3, c4)                        \
    do {                                                                       \
        float _g0 = fminf(a0, c0);                                             \
        float _g1 = fminf(fminf(a1, c1), fmaxf(a0, c0));                       \
        float _g2 = fminf(fminf(a2, c2),                                       \
                    fminf(fmaxf(a1, c0), fmaxf(a0, c1)));                      \
        float _g3 = fminf(fminf(a3, c3),                                       \
                    fminf(fmaxf(a2, c0),                                       \
                    fminf(fmaxf(a1, c1), fmaxf(a0, c2))));                     \
        float _g4 = fminf(fminf(a4, c4),                                       \
                    fminf(fmaxf(a3, c0),                                       \
                    fminf(fmaxf(a2, c1),                                       \
                    fminf(fmaxf(a1, c2), fmaxf(a0, c3)))));                    \
        a0 = _g0; a1 = _g1; a2 = _g2; a3 = _g3; a4 = _g4;                      \
    } while (0)

static __device__ __forceinline__ unsigned key_of(const float4& P, float qqb,
                                                  float nx, float ny, float nz,
                                                  unsigned idxv) {
    float t = fmaf(P.x, nx, fmaf(P.y, ny, fmaf(P.z, nz, P.w + qqb)));
    return (__float_as_uint(t) & 0xFFFFF800u) | idxv;
}

// Stage clouds as float4(x,y,z,|p|^2): i in [0,4096), cloud = i>>11.
__global__ __launch_bounds__(BLOCK) void prep_kernel(const float* __restrict__ src,
                                                     const float* __restrict__ tgt,
                                                     float4* __restrict__ cloud4) {
    int i = blockIdx.x * BLOCK + threadIdx.x;
    if (i >= 2 * NPTS) return;
    int pi = i & (NPTS - 1);
    const float* s = (i >> 11) ? src : tgt;
    float x = s[3 * pi + 0], y = s[3 * pi + 1], z = s[3 * pi + 2];
    float w = fmaf(x, x, fmaf(y, y, z * z));
    cloud4[i] = make_float4(x, y, z, w);
}

__global__ __launch_bounds__(BLOCK, 4) void main_kernel(const float* __restrict__ src,
                                                        const float* __restrict__ tgt,
                                                        const float* __restrict__ noise,
                                                        const float4* __restrict__ cloud4,
                                                        float4* __restrict__ res) {
    __shared__ __align__(16) char smraw[SM_BYTES];
    const int tid = threadIdx.x;

    if (blockIdx.x >= NTAILB) {
        // ---------------- group path: one wave per (tgt-center, cloud) ----------------
        const int lane = tid & 63;
        const int wv = tid >> 6;                         // 0..3
        const int task = (blockIdx.x - NTAILB) * 4 + wv; // 0..4095
        const int m = task >> 1;
        const int cloud = task & 1;
        const float4* c4 = cloud4 + cloud * NPTS;
        float4* buf4 = reinterpret_cast<float4*>(smraw) + wv * CAP;
        unsigned* bufi = reinterpret_cast<unsigned*>(smraw + 4 * CAP * 16) + wv * CAP;

        const float cx = tgt[3 * m + 0], cy = tgt[3 * m + 1], cz = tgt[3 * m + 2];

        // lane map: sub = lane>>4 (0..3), qi = lane&15 (queries 0..9 valid)
        const int sub = lane >> 4;
        const int qi = lane & 15;

        float qx = cx, qy = cy, qz = cz, delta = 0.f;
        if (qi < UPR) {
            int q = m * UPR + qi;
            float nr0 = noise[3 * q + 0], nr1 = noise[3 * q + 1], nr2 = noise[3 * q + 2];
            qx = fmaf(0.05f, nr0, cx);
            qy = fmaf(0.05f, nr1, cy);
            qz = fmaf(0.05f, nr2, cz);
            delta = 0.05f * sqrtf(fmaf(nr0, nr0, fmaf(nr1, nr1, nr2 * nr2)));
        }
        float dmax = delta;
#pragma unroll
        for (int s = 1; s < 64; s <<= 1) dmax = fmaxf(dmax, __shfl_xor(dmax, s, 64));

        const float ncx = -2.f * cx, ncy = -2.f * cy, ncz = -2.f * cz;
        const float ccb = fmaf(cx, cx, fmaf(cy, cy, cz * cz)) + BIAS;

        // pass 1: per-lane top-2 center distances, butterfly -> r5 upper bound
        float f0 = INFINITY, f1 = INFINITY;
#pragma unroll 4
        for (int j = 0; j < NPTS / 64; ++j) {
            float4 P = c4[j * 64 + lane];
            float s = fmaf(P.x, ncx, fmaf(P.y, ncy, fmaf(P.z, ncz, P.w))) + ccb;
            f1 = fminf(f1, fmaxf(f0, s));
            f0 = fminf(f0, s);
        }
        float f2 = INFINITY, f3 = INFINITY, f4 = INFINITY;
#pragma unroll
        for (int s = 1; s < 64; s <<= 1) {
            float h0 = __shfl_xor(f0, s, 64), h1 = __shfl_xor(f1, s, 64),
                  h2 = __shfl_xor(f2, s, 64), h3 = __shfl_xor(f3, s, 64),
                  h4 = __shfl_xor(f4, s, 64);
            FMERGE5(f0, f1, f2, f3, f4, h0, h1, h2, h3, h4);
        }
        float r5ub = sqrtf(fmaxf(f4 - BIAS, 0.f) + 2e-5f) + 1e-3f;
        float bnd = r5ub + 2.f * dmax + 1e-3f;
        float S = fmaf(bnd, bnd, BIAS + 1e-5f);

        const float nqx = -2.f * qx, nqy = -2.f * qy, nqz = -2.f * qz;
        const float qqb = fmaf(qx, qx, fmaf(qy, qy, qz * qz)) + BIAS;

        unsigned b0 = ~0u, b1 = ~0u, b2 = ~0u, b3 = ~0u, b4 = ~0u;

        auto drain = [&](unsigned count) {
            for (unsigned k = sub; k < count; k += 4) {
                float4 P = buf4[k];
                unsigned id = bufi[k];
                float su = fmaf(P.x, nqx, fmaf(P.y, nqy, fmaf(P.z, nqz, P.w + qqb)));
                unsigned key = (__float_as_uint(su) & 0xFFFFF800u) | id;
                INSERT1(b0, b1, b2, b3, b4, key);
            }
        };

        // pass 2: scan + ballot/mbcnt compaction into per-wave LDS buffer
        unsigned scnt = 0;
        for (int j = 0; j < NPTS / 64; ++j) {
            const int base = j * 64;
            float4 P = c4[base + lane];
            float s = fmaf(P.x, ncx, fmaf(P.y, ncy, fmaf(P.z, ncz, P.w))) + ccb;
            bool pred = s <= S;
            unsigned long long mask = __ballot(pred);
            unsigned pre = __builtin_amdgcn_mbcnt_hi((unsigned)(mask >> 32),
                           __builtin_amdgcn_mbcnt_lo((unsigned)mask, 0));
            if (pred) {
                buf4[scnt + pre] = P;
                bufi[scnt + pre] = (unsigned)(base + lane);
            }
            scnt += (unsigned)__popcll(mask);
            if (scnt > CAP - 64) { drain(scnt); scnt = 0; }   // overflow (rare), exact
        }
        drain(scnt);

        // reunify the 4 subs (xor 16, 32)
        SHFL_MERGE(b0, b1, b2, b3, b4, 16);
        SHFL_MERGE(b0, b1, b2, b3, b4, 32);

        if (sub == 0 && qi < UPR) {
            unsigned ks[KNN] = { b0, b1, b2, b3, b4 };
            float wsum = 0.f, gx = 0.f, gy = 0.f, gz = 0.f;
#pragma unroll
            for (int i = 0; i < KNN; ++i) {
                unsigned id = ks[i] & 0x7FFu;
                float4 P = c4[id];
                float dx = qx - P.x, dy = qy - P.y, dz = qz - P.z;
                float dd = fmaf(dx, dx, fmaf(dy, dy, dz * dz));
                float inv = 1.0f / (dd + 1e-8f);
                wsum += inv;
                gx += dx * inv; gy += dy * inv; gz += dz * inv;
            }
            float rs = 1.0f / wsum;
            gx *= rs; gy *= rs; gz *= rs;
            float ex = gx + 1e-10f, ey = gy + 1e-10f, ez = gz + 1e-10f;
            float udf = sqrtf(fmaf(ex, ex, fmaf(ey, ey, ez * ez)));
            res[cloud * QTOT + m * UPR + qi] = make_float4(udf, gx, gy, gz);
        }
        return;
    }

    // ---------------- tail-dense path (R6 machinery, src queries) ----------------
    float4* lds4 = reinterpret_cast<float4*>(smraw);
    const int bb = blockIdx.x;                  // 0..127
    const int cloud = bb & 1;
    const int qbase = NTGTQ + (bb >> 1) * TQPB;
    const float4* c4 = cloud4 + cloud * NPTS;

    for (int t = tid; t < 512; t += BLOCK) {
        int db = (t >> 4) * CH4 + (t & 15) * 4;
        lds4[db + 0] = c4[4 * t + 0];
        lds4[db + 1] = c4[4 * t + 1];
        lds4[db + 2] = c4[4 * t + 2];
        lds4[db + 3] = c4[4 * t + 3];
    }

    const int sub = tid & 31;
    const int u = tid >> 5;                     // 0..7

    float nx[4], ny[4], nz[4], qqb[4];
#pragma unroll
    for (int c = 0; c < 4; ++c) {
        int i = qbase + u + 8 * c - NTGTQ;
        float qx = src[3 * i + 0], qy = src[3 * i + 1], qz = src[3 * i + 2];
        nx[c] = -2.f * qx; ny[c] = -2.f * qy; nz[c] = -2.f * qz;
        qqb[c] = fmaf(qx, qx, fmaf(qy, qy, qz * qz)) + BIAS;
    }

    __syncthreads();

    unsigned a0 = ~0u, a1 = ~0u, a2 = ~0u, a3 = ~0u, a4 = ~0u;
    unsigned e0 = ~0u, e1 = ~0u, e2 = ~0u, e3 = ~0u, e4 = ~0u;
    unsigned c0 = ~0u, c1 = ~0u, c2 = ~0u, c3 = ~0u, c4v = ~0u;
    unsigned d0 = ~0u, d1 = ~0u, d2 = ~0u, d3 = ~0u, d4 = ~0u;
    {
        const float4* bp = lds4 + sub * CH4;
        unsigned idx = (unsigned)(sub * CHUNK);
#pragma unroll 2
        for (int j = 0; j < CHUNK; j += 2) {
            float4 P = bp[j];
            float4 Q = bp[j + 1];
            unsigned kP, kQ;
            kP = key_of(P, qqb[0], nx[0], ny[0], nz[0], idx);
            kQ = key_of(Q, qqb[0], nx[0], ny[0], nz[0], idx + 1);
            INSERT_PAIR(a0, a1, a2, a3, a4, kP, kQ);
            kP = key_of(P, qqb[1], nx[1], ny[1], nz[1], idx);
            kQ = key_of(Q, qqb[1], nx[1], ny[1], nz[1], idx + 1);
            INSERT_PAIR(e0, e1, e2, e3, e4, kP, kQ);
            kP = key_of(P, qqb[2], nx[2], ny[2], nz[2], idx);
            kQ = key_of(Q, qqb[2], nx[2], ny[2], nz[2], idx + 1);
            INSERT_PAIR(c0, c1, c2, c3, c4v, kP, kQ);
            kP = key_of(P, qqb[3], nx[3], ny[3], nz[3], idx);
            kQ = key_of(Q, qqb[3], nx[3], ny[3], nz[3], idx + 1);
            INSERT_PAIR(d0, d1, d2, d3, d4, kP, kQ);
            idx += 2;
        }
    }

#pragma unroll
    for (int mask = 1; mask <= 16; mask <<= 1) {
        SHFL_MERGE(a0, a1, a2, a3, a4, mask);
        SHFL_MERGE(e0, e1, e2, e3, e4, mask);
        SHFL_MERGE(c0, c1, c2, c3, c4v, mask);
        SHFL_MERGE(d0, d1, d2, d3, d4, mask);
    }

    const int s2 = sub & 3;
    unsigned k0 = s2 == 0 ? a0 : s2 == 1 ? e0 : s2 == 2 ? c0 : d0;
    unsigned k1 = s2 == 0 ? a1 : s2 == 1 ? e1 : s2 == 2 ? c1 : d1;
    unsigned k2 = s2 == 0 ? a2 : s2 == 1 ? e2 : s2 == 2 ? c2 : d2;
    unsigned k3 = s2 == 0 ? a3 : s2 == 1 ? e3 : s2 == 2 ? c3 : d3;
    unsigned k4 = s2 == 0 ? a4 : s2 == 1 ? e4 : s2 == 2 ? c4v : d4;
    float snx = s2 == 0 ? nx[0] : s2 == 1 ? nx[1] : s2 == 2 ? nx[2] : nx[3];
    float sny = s2 == 0 ? ny[0] : s2 == 1 ? ny[1] : s2 == 2 ? ny[2] : ny[3];
    float snz = s2 == 0 ? nz[0] : s2 == 1 ? nz[1] : s2 == 2 ? nz[2] : nz[3];
    float qx = -0.5f * snx, qy = -0.5f * sny, qz = -0.5f * snz;

    unsigned ks[KNN] = { k0, k1, k2, k3, k4 };
    float wsum = 0.f, gx = 0.f, gy = 0.f, gz = 0.f;
#pragma unroll
    for (int i = 0; i < KNN; ++i) {
        unsigned id = ks[i] & 0x7FFu;
        float4 P = lds4[(id >> 6) * CH4 + (id & 63u)];
        float dx = qx - P.x, dy = qy - P.y, dz = qz - P.z;
        float dd = fmaf(dx, dx, fmaf(dy, dy, dz * dz));
        float inv = 1.0f / (dd + 1e-8f);
        wsum += inv;
        gx += dx * inv; gy += dy * inv; gz += dz * inv;
    }
    float rs = 1.0f / wsum;
    gx *= rs; gy *= rs; gz *= rs;
    float ex = gx + 1e-10f, ey = gy + 1e-10f, ez = gz + 1e-10f;
    float udf = sqrtf(fmaf(ex, ex, fmaf(ey, ey, ez * ez)));

    if (sub < 4) {
        int q = qbase + u + 8 * s2;
        res[cloud * QTOT + q] = make_float4(udf, gx, gy, gz);
    }
}

__global__ __launch_bounds__(BLOCK2) void loss_kernel(const float4* __restrict__ res,
                                                      float* __restrict__ acc,
                                                      unsigned* __restrict__ cnt,
                                                      float* __restrict__ out) {
    const int q = blockIdx.x * BLOCK2 + threadIdx.x;
    float4 t = res[q];
    float4 s = res[QTOT + q];
    float ue  = fabsf(t.x - s.x);
    float uge = fabsf(s.y - t.y) + fabsf(s.z - t.z) + fabsf(s.w - t.w);
    float sum = ue + uge;
    float term = sum * expf(-3.0f * sum);

#pragma unroll
    for (int m = 1; m < 64; m <<= 1) term += __shfl_xor(term, m, 64);
    __shared__ float red[BLOCK2 / 64];
    if ((threadIdx.x & 63) == 0) red[threadIdx.x >> 6] = term;
    __syncthreads();

    if (threadIdx.x == 0) {
        float partial = 0.f;
#pragma unroll
        for (int w = 0; w < BLOCK2 / 64; ++w) partial += red[w];
        atomicAdd(acc, partial);
        __threadfence();
        unsigned done = atomicAdd(cnt, 1u);
        if (done == NB2 - 1) {
            float sfin = atomicAdd(acc, 0.0f);
            out[0] = sfin / (float)QTOT;
        }
    }
}

extern "C" void kernel_launch(void* const* d_in, const int* in_sizes, int n_in,
                              void* d_out, int out_size, void* d_ws, size_t ws_size,
                              hipStream_t stream) {
    const float* src   = (const float*)d_in[0];
    const float* tgt   = (const float*)d_in[1];
    const float* noise = (const float*)d_in[2];
    float* out = (float*)d_out;

    float* acc = (float*)d_ws;                                     // ws[0]
    unsigned* cnt = (unsigned*)d_ws + 1;                           // ws[1]
    float4* cloud4 = (float4*)((char*)d_ws + 16);                  // 4096 float4 = 64 KB
    float4* res = (float4*)((char*)d_ws + 16 + 2 * NPTS * 16);     // 2*QTOT float4

    hipMemsetAsync(d_ws, 0, 8, stream);
    prep_kernel<<<(2 * NPTS + BLOCK - 1) / BLOCK, BLOCK, 0, stream>>>(src, tgt, cloud4);
    main_kernel<<<NB_MAIN, BLOCK, 0, stream>>>(src, tgt, noise, cloud4, res);
    loss_kernel<<<NB2, BLOCK2, 0, stream>>>(res, acc, cnt, out);
}

// Round 9
// 79.955 us; speedup vs baseline: 1.3972x; 1.0758x over previous
//
#include <hip/hip_runtime.h>

// DirDist_P2P: fused jittered-query construction + exact 5-NN against two
// 2048-point clouds + inverse-distance UDF/grad + weighted scalar loss.
//
// R9: stall-focused rework. Group path (20480 jittered queries in groups of
// 10 around tgt centers): pass1 center-scan -> r5 upper bound; pass2
// ballot+mbcnt compaction of accepted points into per-wave LDS as
// float4(x,y,z,idxbits); sentinel-padded fixed-stride drain (INSERT_PAIR of
// two independent ds_read_b128 per iter) into per-query chains; xor16/32
// merges. Tail (2048 src queries, no jitter -> no grouping): one wave per
// (query,cloud), per-lane top-5 + 6-round butterfly merge, no LDS.
// LDS = 20.5 KB (compaction only) + launch_bounds(256,7) -> 7 blocks/CU
// = 28 waves/CU for latency hiding. No prep kernel (raw 12-B point loads).
// Harness ws poison (~39 us, 268 MB fill) is a fixed floor outside kernel
// control.

#define NPTS   2048
#define UPR    10
#define KNN    5
#define NTGTQ  (NPTS * UPR)           // 20480
#define QTOT   (NTGTQ + NPTS)         // 22528
#define BLOCK  256
#define NGRPB  1024                   // group blocks (4 wave-tasks each)
#define NTAILB 1024                   // tail blocks (4 wave-tasks each)
#define NB_MAIN (NGRPB + NTAILB)      // 2048
#define CAP    320                    // accepted-point buffer per wave (float4)
#define BLOCK2 256
#define NB2    (QTOT / BLOCK2)        // 88

static __device__ __forceinline__ unsigned umin32(unsigned a, unsigned b) { return a < b ? a : b; }
static __device__ __forceinline__ unsigned umax32(unsigned a, unsigned b) { return a < b ? b : a; }

// single-candidate sorted insert (ascending 5-list), 9 min/max
#define INSERT1(A0, A1, A2, A3, A4, P)                                         \
    do {                                                                       \
        unsigned _p = (P);                                                     \
        A4 = umin32(A4, umax32(A3, _p));                                       \
        A3 = umin32(A3, umax32(A2, _p));                                       \
        A2 = umin32(A2, umax32(A1, _p));                                       \
        A1 = umin32(A1, umax32(A0, _p));                                       \
        A0 = umin32(A0, _p);                                                   \
    } while (0)

// pair insert (presort + merge-path), 14 min/max
#define INSERT_PAIR(A0, A1, A2, A3, A4, P, Q)                                  \
    do {                                                                       \
        unsigned _u = umin32(P, Q), _v = umax32(P, Q);                         \
        unsigned _m0u = umax32(A0, _u), _m1u = umax32(A1, _u);                 \
        unsigned _m2u = umax32(A2, _u), _m3u = umax32(A3, _u);                 \
        unsigned _m0v = umax32(A0, _v), _m1v = umax32(A1, _v);                 \
        unsigned _m2v = umax32(A2, _v);                                        \
        A0 = umin32(A0, _u);                                                   \
        A1 = umin32(umin32(A1, _v), _m0u);                                     \
        A2 = umin32(umin32(A2, _m1u), _m0v);                                   \
        A3 = umin32(umin32(A3, _m2u), _m1v);                                   \
        A4 = umin32(umin32(A4, _m3u), _m2v);                                   \
    } while (0)

// 5+5 sorted merge (merge-path), u32 keys
#define MERGE5(a0, a1, a2, a3, a4, c0, c1, c2, c3, c4)                         \
    do {                                                                       \
        unsigned _n0 = umin32(a0, c0);                                         \
        unsigned _n1 = umin32(umin32(a1, c1), umax32(a0, c0));                 \
        unsigned _n2 = umin32(umin32(a2, c2),                                  \
                       umin32(umax32(a1, c0), umax32(a0, c1)));                \
        unsigned _n3 = umin32(umin32(a3, c3),                                  \
                       umin32(umax32(a2, c0),                                  \
                       umin32(umax32(a1, c1), umax32(a0, c2))));               \
        unsigned _n4 = umin32(umin32(a4, c4),                                  \
                       umin32(umax32(a3, c0),                                  \
                       umin32(umax32(a2, c1),                                  \
                       umin32(umax32(a1, c2), umax32(a0, c3)))));              \
        a0 = _n0; a1 = _n1; a2 = _n2; a3 = _n3; a4 = _n4;                      \
    } while (0)

#define SHFL_MERGE(a0, a1, a2, a3, a4, mask)                                   \
    do {                                                                       \
        unsigned _c0 = (unsigned)__shfl_xor((int)a0, mask, 64);                \
        unsigned _c1 = (unsigned)__shfl_xor((int)a1, mask, 64);                \
        unsigned _c2 = (unsigned)__shfl_xor((int)a2, mask, 64);                \
        unsigned _c3 = (unsigned)__shfl_xor((int)a3, mask, 64);                \
        unsigned _c4 = (unsigned)__shfl_xor((int)a4, mask, 64);                \
        MERGE5(a0, a1, a2, a3, a4, _c0, _c1, _c2, _c3, _c4);                   \
    } while (0)

// 5+5 sorted merge, f32 keys
#define FMERGE5(a0, a1, a2, a3, a4, c0, c1, c2, c3, c4)                        \
    do {                                                                       \
        float _g0 = fminf(a0, c0);                                             \
        float _g1 = fminf(fminf(a1, c1), fmaxf(a0, c0));                       \
        float _g2 = fminf(fminf(a2, c2),                                       \
                    fminf(fmaxf(a1, c0), fmaxf(a0, c1)));                      \
        float _g3 = fminf(fminf(a3, c3),                                       \
                    fminf(fmaxf(a2, c0),                                       \
                    fminf(fmaxf(a1, c1), fmaxf(a0, c2))));                     \
        float _g4 = fminf(fminf(a4, c4),                                       \
                    fminf(fmaxf(a3, c0),                                       \
                    fminf(fmaxf(a2, c1),                                       \
                    fminf(fmaxf(a1, c2), fmaxf(a0, c3)))));                    \
        a0 = _g0; a1 = _g1; a2 = _g2; a3 = _g3; a4 = _g4;                      \
    } while (0)

__global__ __launch_bounds__(BLOCK, 7) void main_kernel(const float* __restrict__ src,
                                                        const float* __restrict__ tgt,
                                                        const float* __restrict__ noise,
                                                        float4* __restrict__ res) {
    __shared__ float4 buf[4 * CAP];   // 20480 B: per-wave compaction buffers
    const int tid = threadIdx.x;
    const int wv = tid >> 6;
    const int lane = tid & 63;
    float4* buf4 = buf + wv * CAP;
    const float INF = __int_as_float(0x7F800000);

    if (blockIdx.x < NGRPB) {
        // ---------------- group path: one wave per (tgt-center, cloud) ----------------
        const int task = blockIdx.x * 4 + wv;           // 0..4095
        const int m = task >> 1;
        const int cloud = task & 1;
        const float* cp = cloud ? src : tgt;

        const float cx = tgt[3 * m + 0], cy = tgt[3 * m + 1], cz = tgt[3 * m + 2];

        // lane map: sub = lane>>4 (0..3), qi = lane&15 (queries 0..9 valid)
        const int sub = lane >> 4;
        const int qi = lane & 15;

        float qx = cx, qy = cy, qz = cz, delta = 0.f;
        if (qi < UPR) {
            int q = m * UPR + qi;
            float nr0 = noise[3 * q + 0], nr1 = noise[3 * q + 1], nr2 = noise[3 * q + 2];
            qx = fmaf(0.05f, nr0, cx);
            qy = fmaf(0.05f, nr1, cy);
            qz = fmaf(0.05f, nr2, cz);
            delta = 0.05f * sqrtf(fmaf(nr0, nr0, fmaf(nr1, nr1, nr2 * nr2)));
        }
        float dmax = delta;
#pragma unroll
        for (int s = 1; s < 64; s <<= 1) dmax = fmaxf(dmax, __shfl_xor(dmax, s, 64));

        // pass 1: per-lane top-2 exact center d2, butterfly -> r5 upper bound
        float f0 = INF, f1 = INF;
#pragma unroll 4
        for (int j = 0; j < NPTS / 64; ++j) {
            int i = j * 64 + lane;
            float px = cp[3 * i + 0], py = cp[3 * i + 1], pz = cp[3 * i + 2];
            float dx = px - cx, dy = py - cy, dz = pz - cz;
            float s = fmaf(dx, dx, fmaf(dy, dy, dz * dz));
            f1 = fminf(f1, fmaxf(f0, s));
            f0 = fminf(f0, s);
        }
        float f2 = INF, f3 = INF, f4 = INF;
#pragma unroll
        for (int s = 1; s < 64; s <<= 1) {
            float h0 = __shfl_xor(f0, s, 64), h1 = __shfl_xor(f1, s, 64),
                  h2 = __shfl_xor(f2, s, 64), h3 = __shfl_xor(f3, s, 64),
                  h4 = __shfl_xor(f4, s, 64);
            FMERGE5(f0, f1, f2, f3, f4, h0, h1, h2, h3, h4);
        }
        // accept radius: r5ub + 2*dmax with fp slack (d2 exact >= 0 here)
        float bnd = sqrtf(f4) + 2.f * dmax + 2e-3f;
        float S = fmaf(bnd, bnd, 1e-6f);

        unsigned b0 = ~0u, b1 = ~0u, b2 = ~0u, b3 = ~0u, b4 = ~0u;

        auto drain = [&](unsigned count) {
            // pad to multiple of 8 with inf-sentinels (key 0x7F800000: never wins)
            if (lane < 8) buf4[count + lane] = make_float4(INF, INF, INF, 0.f);
            unsigned cnt8 = (count + 7u) & ~7u;
            for (unsigned k = sub; k < cnt8; k += 8) {
                float4 P = buf4[k];
                float4 Q = buf4[k + 4];
                float dxp = P.x - qx, dyp = P.y - qy, dzp = P.z - qz;
                float dp = fmaf(dxp, dxp, fmaf(dyp, dyp, dzp * dzp));
                unsigned kP = (__float_as_uint(dp) & 0xFFFFF800u) |
                              (__float_as_uint(P.w) & 0x7FFu);
                float dxq = Q.x - qx, dyq = Q.y - qy, dzq = Q.z - qz;
                float dq = fmaf(dxq, dxq, fmaf(dyq, dyq, dzq * dzq));
                unsigned kQ = (__float_as_uint(dq) & 0xFFFFF800u) |
                              (__float_as_uint(Q.w) & 0x7FFu);
                INSERT_PAIR(b0, b1, b2, b3, b4, kP, kQ);
            }
        };

        // pass 2: rescan + ballot/mbcnt compaction (x,y,z,idxbits)
        unsigned scnt = 0;
        for (int j = 0; j < NPTS / 64; ++j) {
            int i = j * 64 + lane;
            float px = cp[3 * i + 0], py = cp[3 * i + 1], pz = cp[3 * i + 2];
            float dx = px - cx, dy = py - cy, dz = pz - cz;
            float s = fmaf(dx, dx, fmaf(dy, dy, dz * dz));
            bool pred = s <= S;
            unsigned long long mask = __ballot(pred);
            unsigned pre = __builtin_amdgcn_mbcnt_hi((unsigned)(mask >> 32),
                           __builtin_amdgcn_mbcnt_lo((unsigned)mask, 0));
            if (pred) buf4[scnt + pre] = make_float4(px, py, pz, __uint_as_float((unsigned)i));
            scnt += (unsigned)__popcll(mask);
            if (scnt > CAP - 72) { drain(scnt); scnt = 0; }   // overflow (rare), exact
        }
        drain(scnt);

        // reunify the 4 subs (xor 16, 32)
        SHFL_MERGE(b0, b1, b2, b3, b4, 16);
        SHFL_MERGE(b0, b1, b2, b3, b4, 32);

        if (sub == 0 && qi < UPR) {
            unsigned ks[KNN] = { b0, b1, b2, b3, b4 };
            float wsum = 0.f, gx = 0.f, gy = 0.f, gz = 0.f;
#pragma unroll
            for (int i = 0; i < KNN; ++i) {
                unsigned id = ks[i] & 0x7FFu;
                float px = cp[3 * id + 0], py = cp[3 * id + 1], pz = cp[3 * id + 2];
                float dx = qx - px, dy = qy - py, dz = qz - pz;
                float dd = fmaf(dx, dx, fmaf(dy, dy, dz * dz));
                float inv = 1.0f / (dd + 1e-8f);
                wsum += inv;
                gx += dx * inv; gy += dy * inv; gz += dz * inv;
            }
            float rs = 1.0f / wsum;
            gx *= rs; gy *= rs; gz *= rs;
            float ex = gx + 1e-10f, ey = gy + 1e-10f, ez = gz + 1e-10f;
            float udf = sqrtf(fmaf(ex, ex, fmaf(ey, ey, ez * ez)));
            res[cloud * QTOT + m * UPR + qi] = make_float4(udf, gx, gy, gz);
        }
        return;
    }

    // ---------------- tail path: one wave per (src-query, cloud), no LDS ----------------
    const int ti = (blockIdx.x - NGRPB) * 4 + wv;       // 0..4095
    const int i0 = ti >> 1;                             // src point index
    const int cloud = ti & 1;
    const float* cp = cloud ? src : tgt;

    const float qx = src[3 * i0 + 0], qy = src[3 * i0 + 1], qz = src[3 * i0 + 2];

    unsigned b0 = ~0u, b1 = ~0u, b2 = ~0u, b3 = ~0u, b4 = ~0u;
#pragma unroll 4
    for (int j = 0; j < NPTS / 64; j += 2) {
        int i1 = j * 64 + lane;
        int i2 = i1 + 64;
        float p1x = cp[3 * i1 + 0], p1y = cp[3 * i1 + 1], p1z = cp[3 * i1 + 2];
        float p2x = cp[3 * i2 + 0], p2y = cp[3 * i2 + 1], p2z = cp[3 * i2 + 2];
        float dx1 = p1x - qx, dy1 = p1y - qy, dz1 = p1z - qz;
        float d1 = fmaf(dx1, dx1, fmaf(dy1, dy1, dz1 * dz1));
        unsigned k1 = (__float_as_uint(d1) & 0xFFFFF800u) | (unsigned)i1;
        float dx2 = p2x - qx, dy2 = p2y - qy, dz2 = p2z - qz;
        float d2 = fmaf(dx2, dx2, fmaf(dy2, dy2, dz2 * dz2));
        unsigned k2 = (__float_as_uint(d2) & 0xFFFFF800u) | (unsigned)i2;
        INSERT_PAIR(b0, b1, b2, b3, b4, k1, k2);
    }

#pragma unroll
    for (int mask = 1; mask < 64; mask <<= 1) {
        SHFL_MERGE(b0, b1, b2, b3, b4, mask);
    }

    // all lanes hold the identical final list; compute epilogue, lane 0 writes
    unsigned ks[KNN] = { b0, b1, b2, b3, b4 };
    float wsum = 0.f, gx = 0.f, gy = 0.f, gz = 0.f;
#pragma unroll
    for (int i = 0; i < KNN; ++i) {
        unsigned id = ks[i] & 0x7FFu;
        float px = cp[3 * id + 0], py = cp[3 * id + 1], pz = cp[3 * id + 2];
        float dx = qx - px, dy = qy - py, dz = qz - pz;
        float dd = fmaf(dx, dx, fmaf(dy, dy, dz * dz));
        float inv = 1.0f / (dd + 1e-8f);
        wsum += inv;
        gx += dx * inv; gy += dy * inv; gz += dz * inv;
    }
    float rs = 1.0f / wsum;
    gx *= rs; gy *= rs; gz *= rs;
    float ex = gx + 1e-10f, ey = gy + 1e-10f, ez = gz + 1e-10f;
    float udf = sqrtf(fmaf(ex, ex, fmaf(ey, ey, ez * ez)));

    if (lane == 0) {
        res[cloud * QTOT + NTGTQ + i0] = make_float4(udf, gx, gy, gz);
    }
}

__global__ __launch_bounds__(BLOCK2) void loss_kernel(const float4* __restrict__ res,
                                                      float* __restrict__ acc,
                                                      unsigned* __restrict__ cnt,
                                                      float* __restrict__ out) {
    const int q = blockIdx.x * BLOCK2 + threadIdx.x;
    float4 t = res[q];
    float4 s = res[QTOT + q];
    float ue  = fabsf(t.x - s.x);
    float uge = fabsf(s.y - t.y) + fabsf(s.z - t.z) + fabsf(s.w - t.w);
    float sum = ue + uge;
    float term = sum * expf(-3.0f * sum);

#pragma unroll
    for (int m = 1; m < 64; m <<= 1) term += __shfl_xor(term, m, 64);
    __shared__ float red[BLOCK2 / 64];
    if ((threadIdx.x & 63) == 0) red[threadIdx.x >> 6] = term;
    __syncthreads();

    if (threadIdx.x == 0) {
        float partial = 0.f;
#pragma unroll
        for (int w = 0; w < BLOCK2 / 64; ++w) partial += red[w];
        atomicAdd(acc, partial);
        __threadfence();
        unsigned done = atomicAdd(cnt, 1u);
        if (done == NB2 - 1) {
            float sfin = atomicAdd(acc, 0.0f);
            out[0] = sfin / (float)QTOT;
        }
    }
}

extern "C" void kernel_launch(void* const* d_in, const int* in_sizes, int n_in,
                              void* d_out, int out_size, void* d_ws, size_t ws_size,
                              hipStream_t stream) {
    const float* src   = (const float*)d_in[0];
    const float* tgt   = (const float*)d_in[1];
    const float* noise = (const float*)d_in[2];
    float* out = (float*)d_out;

    float* acc = (float*)d_ws;                                 // ws[0]
    unsigned* cnt = (unsigned*)d_ws + 1;                       // ws[1]
    float4* res = (float4*)((char*)d_ws + 16);                 // 2*QTOT float4

    hipMemsetAsync(d_ws, 0, 8, stream);
    main_kernel<<<NB_MAIN, BLOCK, 0, stream>>>(src, tgt, noise, res);
    loss_kernel<<<NB2, BLOCK2, 0, stream>>>(res, acc, cnt, out);
}